// Round 8
// baseline (839.149 us; speedup 1.0000x reference)
//
#include <hip/hip_runtime.h>
#include <hip/hip_bf16.h>

#define D_MODEL 1024
#define N_LAYER 4
#define D_INNER 2048
#define D_STATE 16
#define D_CONV  4
#define DT_RANK 64
#define SEQ_L   1024
#define VOCAB   50280
#define VOCAB_PAD 50304   // 393*128
#define NCHUNK  32
#define CLEN    32

typedef __attribute__((ext_vector_type(8))) short short8;
typedef __attribute__((ext_vector_type(4))) float f32x4;

typedef __attribute__((address_space(1))) const unsigned GUint;
typedef __attribute__((address_space(3))) unsigned LUint;

__device__ __forceinline__ float silu_f(float x) {
    return x / (1.0f + __expf(-x));
}
__device__ __forceinline__ float softplus_f(float x) {
    return fmaxf(x, 0.0f) + log1pf(__expf(-fabsf(x)));
}
__device__ __forceinline__ ushort f2bf(float f) {
    union { float f; unsigned u; } uf; uf.f = f;
    unsigned r = uf.u + 0x7FFF + ((uf.u >> 16) & 1);   // RNE
    return (ushort)(r >> 16);
}

// ---------------- fp32 -> bf16 bulk convert ----------------
__global__ void f32_to_bf16_kernel(const float* __restrict__ in,
                                   ushort* __restrict__ out, int n4) {
    int i = blockIdx.x * 256 + threadIdx.x;
    if (i >= n4) return;
    float4 v = *(const float4*)(in + (size_t)i * 4);
    ushort4 o;
    o.x = f2bf(v.x); o.y = f2bf(v.y); o.z = f2bf(v.z); o.w = f2bf(v.w);
    *(ushort4*)(out + (size_t)i * 4) = o;
}

// x_proj weights: (4,96,2048) fp32 -> (4,128,2048) bf16 with zero-filled pad rows
__global__ void xpw_convert_kernel(const float* __restrict__ src,
                                   ushort* __restrict__ dst) {
    int q = blockIdx.x * 256 + threadIdx.x;   // quad index, total 4*128*512
    int layer = q / (128 * 512);
    int rq    = q % (128 * 512);
    int row   = rq / 512;
    int cq    = rq % 512;
    ushort4 o;
    if (row < 96) {
        float4 v = *(const float4*)(src + ((size_t)layer * 96 + row) * 2048 + cq * 4);
        o.x = f2bf(v.x); o.y = f2bf(v.y); o.z = f2bf(v.z); o.w = f2bf(v.w);
    } else {
        o.x = o.y = o.z = o.w = 0;
    }
    *(ushort4*)(dst + (size_t)q * 4) = o;
}

// ---------------- embedding gather (writes part slot 0) ----------------
__global__ void embed_kernel(const int* __restrict__ ids,
                             const float* __restrict__ emb,
                             float* __restrict__ hidden) {
    int l = blockIdx.x;
    int t = threadIdx.x;
    int id = ids[l];
    float4 v = *(const float4*)(emb + (size_t)id * D_MODEL + t * 4);
    *(float4*)(hidden + (size_t)l * D_MODEL + t * 4) = v;
}

// ---------------- residual add + RMSNorm -> bf16 x ----------------
// res = (add? res : 0) + sum_{s<nparts} part[s]; xout = rmsnorm(res)*w
__global__ void add_rmsnorm_kernel(float* __restrict__ res,
                                   const float* __restrict__ part,
                                   const float* __restrict__ w,
                                   ushort* __restrict__ xout,
                                   int add, int nparts) {
    int l = blockIdx.x;
    int t = threadIdx.x;
    size_t base = (size_t)l * D_MODEL + t * 4;
    float4 r;
    if (add) r = *(const float4*)(res + base);
    else     r = make_float4(0.f, 0.f, 0.f, 0.f);
    for (int s = 0; s < nparts; ++s) {
        float4 hv = *(const float4*)(part + (size_t)s * SEQ_L * D_MODEL + base);
        r.x += hv.x; r.y += hv.y; r.z += hv.z; r.w += hv.w;
    }
    *(float4*)(res + base) = r;
    float ss = r.x * r.x + r.y * r.y + r.z * r.z + r.w * r.w;
    #pragma unroll
    for (int off = 32; off > 0; off >>= 1) ss += __shfl_down(ss, off, 64);
    __shared__ float sred[4];
    if ((t & 63) == 0) sred[t >> 6] = ss;
    __syncthreads();
    float tot = sred[0] + sred[1] + sred[2] + sred[3];
    float scale = rsqrtf(tot * (1.0f / (float)D_MODEL) + 1e-5f);
    float4 wv = *(const float4*)(w + t * 4);
    ushort4 o;
    o.x = f2bf(r.x * scale * wv.x);
    o.y = f2bf(r.y * scale * wv.y);
    o.z = f2bf(r.z * scale * wv.z);
    o.w = f2bf(r.w * scale * wv.w);
    *(ushort4*)(xout + base) = o;
}

// ---------------- bf16 MFMA TN GEMM, global_load_lds staging ----------------
// Linear LDS [128][32], double-buffered, 1 barrier/K-step. XCD-banded decode.
// Source-chunk pre-swizzle + matching read XOR -> 0 bank conflicts (rule #21).
// SPLIT=1: K-split partial outputs to C + ks*pstride (non-atomic).
// W rows must be readable up to padded N (pad rows zero-filled); M%128==0.
template<int SPLIT>
__global__ void gemm_bf16_gld_kernel(const ushort* __restrict__ A,
                                     const ushort* __restrict__ W,
                                     float* __restrict__ C,
                                     int N, int K, int lda, int ldc,
                                     int MB, int KS, int pstride) {
    __shared__ ushort As[2][128][32];
    __shared__ ushort Ws[2][128][32];
    const int t  = threadIdx.x;
    const int T  = gridDim.x >> 3;
    const int id = blockIdx.x;
    const int j  = (id & 7) * T + (id >> 3);
    const int ks  = j % KS;
    const int rem = j / KS;
    const int m0 = (rem % MB) * 128;
    const int n0 = (rem / MB) * 128;
    const int kchunk = K / KS;
    const int kbeg = ks * kchunk;
    const int kend = kbeg + kchunk;

    const int lane = t & 63;
    const int w    = t >> 6;                 // wave 0..3
    const int srow = w * 16 + (lane >> 2);
    const int scol = (((lane & 3) ^ ((lane >> 3) & 3)) * 8);   // swizzled src chunk
    const ushort* Ag0 = A + (size_t)(m0 + srow) * lda + scol;
    const ushort* Ag1 = A + (size_t)(m0 + srow + 64) * lda + scol;
    const ushort* Wg0 = W + (size_t)(n0 + srow) * K + scol;
    const ushort* Wg1 = W + (size_t)(n0 + srow + 64) * K + scol;

    const int wm = (t >> 7) & 1;
    const int wn = (t >> 6) & 1;
    const int lr = lane & 15;
    const int lk = lane >> 4;
    const int swz = (lr >> 1) & 3;           // read-side XOR pattern

    f32x4 acc[4][4] = {};

#define STAGE_GLD(buf, kk)                                                        \
    do {                                                                          \
        __builtin_amdgcn_global_load_lds((GUint*)(Ag0 + (kk)),                    \
            (LUint*)&As[buf][w * 16][0], 16, 0, 0);                               \
        __builtin_amdgcn_global_load_lds((GUint*)(Ag1 + (kk)),                    \
            (LUint*)&As[buf][64 + w * 16][0], 16, 0, 0);                          \
        __builtin_amdgcn_global_load_lds((GUint*)(Wg0 + (kk)),                    \
            (LUint*)&Ws[buf][w * 16][0], 16, 0, 0);                               \
        __builtin_amdgcn_global_load_lds((GUint*)(Wg1 + (kk)),                    \
            (LUint*)&Ws[buf][64 + w * 16][0], 16, 0, 0);                          \
    } while (0)

    STAGE_GLD(0, kbeg);
    int buf = 0;
    for (int k0 = kbeg;;) {
        __syncthreads();   // vmcnt(0)+lgkmcnt(0)+barrier: buf ready
        const bool more = (k0 + 32) < kend;
        if (more) STAGE_GLD(buf ^ 1, k0 + 32);

        short8 af[4], bfr[4];
        #pragma unroll
        for (int m = 0; m < 4; ++m)
            af[m] = *(const short8*)&As[buf][wm * 64 + m * 16 + lr][(lk ^ swz) * 8];
        #pragma unroll
        for (int n = 0; n < 4; ++n)
            bfr[n] = *(const short8*)&Ws[buf][wn * 64 + n * 16 + lr][(lk ^ swz) * 8];
        #pragma unroll
        for (int m = 0; m < 4; ++m)
            #pragma unroll
            for (int n = 0; n < 4; ++n)
                acc[m][n] = __builtin_amdgcn_mfma_f32_16x16x32_bf16(
                    af[m], bfr[n], acc[m][n], 0, 0, 0);

        if (!more) break;
        buf ^= 1;
        k0 += 32;
    }
#undef STAGE_GLD

    float* Cp = SPLIT ? (C + (size_t)ks * pstride) : C;
    #pragma unroll
    for (int m = 0; m < 4; ++m) {
        const int row = m0 + wm * 64 + m * 16 + lk * 4;
        #pragma unroll
        for (int n = 0; n < 4; ++n) {
            const int col = n0 + wn * 64 + n * 16 + lr;
            if (col < N) {
                #pragma unroll
                for (int r = 0; r < 4; ++r)
                    Cp[(size_t)(row + r) * ldc + col] = acc[m][n][r];
            }
        }
    }
}

// ---------------- xdbl 32-partial reduce (+ bf16 dt_r emit) ----------------
__global__ void xdbl_reduce_kernel(const float* __restrict__ part,
                                   float* __restrict__ out,
                                   ushort* __restrict__ dtr_b) {
    int i = blockIdx.x * 256 + threadIdx.x;   // quad index, 24576 total
    float4 acc = make_float4(0.f, 0.f, 0.f, 0.f);
    #pragma unroll
    for (int s = 0; s < 32; ++s) {
        float4 v = *(const float4*)(part + (size_t)s * SEQ_L * 96 + (size_t)i * 4);
        acc.x += v.x; acc.y += v.y; acc.z += v.z; acc.w += v.w;
    }
    *(float4*)(out + (size_t)i * 4) = acc;
    int c = (i * 4) % 96;
    if (c < 64) {
        int r = (i * 4) / 96;
        ushort4 o;
        o.x = f2bf(acc.x); o.y = f2bf(acc.y); o.z = f2bf(acc.z); o.w = f2bf(acc.w);
        *(ushort4*)(dtr_b + (size_t)r * 64 + c) = o;
    }
}

// ---------------- depthwise causal conv (k=4) + silu, sums 2 xz partials ----
__global__ void conv_silu_kernel(const float* __restrict__ xz,
                                 const float* __restrict__ cw,
                                 const float* __restrict__ cb,
                                 float* __restrict__ u,
                                 ushort* __restrict__ u_b) {
    int idx = blockIdx.x * 256 + threadIdx.x;
    int l = idx >> 11;
    int c = idx & 2047;
    float acc = cb[c];
    float w0 = cw[c * 4 + 0], w1 = cw[c * 4 + 1], w2 = cw[c * 4 + 2], w3 = cw[c * 4 + 3];
#define XP(ll) (xz[(size_t)(ll) * 4096 + c] + xz[(size_t)SEQ_L * 4096 + (size_t)(ll) * 4096 + c])
    if (l >= 3) acc = fmaf(XP(l - 3), w0, acc);
    if (l >= 2) acc = fmaf(XP(l - 2), w1, acc);
    if (l >= 1) acc = fmaf(XP(l - 1), w2, acc);
    acc = fmaf(XP(l), w3, acc);
#undef XP
    float s = silu_f(acc);
    u[idx] = s;
    u_b[idx] = f2bf(s);
}

// ---------------- chunked selective scan ----------------
// Pass A: dt = softplus(dtp0 + dtp1 + bias) computed inline from GEMM partials.
__global__ void scan_a_kernel(const float* __restrict__ u,
                              const float* __restrict__ dtp,   // 2 partials
                              const float* __restrict__ dt_bias,
                              const float* __restrict__ xdbl,
                              const float* __restrict__ A_log,
                              float* __restrict__ yloc,     // stride 4096 (xzp0 xp half)
                              float* __restrict__ cumdt,    // [l][d]
                              float* __restrict__ s_end) {  // [d][c][n]
    const int idx = blockIdx.x * 256 + threadIdx.x;   // 65536
    const int d = idx & 2047;
    const int c = idx >> 11;

    float Aa[16];
    #pragma unroll
    for (int q = 0; q < 4; ++q) {
        float4 al = *(const float4*)(A_log + (size_t)d * 16 + q * 4);
        Aa[q * 4 + 0] = -__expf(al.x);
        Aa[q * 4 + 1] = -__expf(al.y);
        Aa[q * 4 + 2] = -__expf(al.z);
        Aa[q * 4 + 3] = -__expf(al.w);
    }
    const float dbias = dt_bias[d];

    float s[16];
    #pragma unroll
    for (int n = 0; n < 16; ++n) s[n] = 0.0f;
    float cd = 0.0f;

    const int l0 = c * CLEN;
    for (int i = 0; i < CLEN; ++i) {
        const int l = l0 + i;
        const float dtl = softplus_f(dtp[(size_t)l * 2048 + d]
                                   + dtp[(size_t)SEQ_L * 2048 + (size_t)l * 2048 + d]
                                   + dbias);
        const float ul  = u[(size_t)l * 2048 + d];
        float Bn[16], Cn[16];
        const float* xbp = xdbl + (size_t)l * 96;
        *(float4*)&Bn[0]  = *(const float4*)(xbp + 64);
        *(float4*)&Bn[4]  = *(const float4*)(xbp + 68);
        *(float4*)&Bn[8]  = *(const float4*)(xbp + 72);
        *(float4*)&Bn[12] = *(const float4*)(xbp + 76);
        *(float4*)&Cn[0]  = *(const float4*)(xbp + 80);
        *(float4*)&Cn[4]  = *(const float4*)(xbp + 84);
        *(float4*)&Cn[8]  = *(const float4*)(xbp + 88);
        *(float4*)&Cn[12] = *(const float4*)(xbp + 92);
        cd += dtl;
        const float dtu = dtl * ul;
        float y = 0.0f;
        #pragma unroll
        for (int n = 0; n < 16; ++n) {
            float dA = __expf(dtl * Aa[n]);
            s[n] = fmaf(s[n], dA, dtu * Bn[n]);
            y = fmaf(s[n], Cn[n], y);
        }
        yloc[(size_t)l * 4096 + d] = y;
        cumdt[(size_t)l * 2048 + d] = cd;
    }
    float* se = s_end + ((size_t)d * NCHUNK + c) * 16;
    #pragma unroll
    for (int q = 0; q < 4; ++q)
        *(float4*)(se + q * 4) = make_float4(s[q * 4], s[q * 4 + 1], s[q * 4 + 2], s[q * 4 + 3]);
}

__global__ void scan_b_kernel(const float* __restrict__ s_end,
                              const float* __restrict__ cumdt,
                              const float* __restrict__ A_log,
                              float* __restrict__ s_in) {
    const int idx = blockIdx.x * 256 + threadIdx.x;   // 32768
    const int d = idx >> 4;
    const int n = idx & 15;
    const float Aa = -__expf(A_log[(size_t)d * 16 + n]);
    float s = 0.0f;
    #pragma unroll
    for (int c = 0; c < NCHUNK; ++c) {
        s_in[((size_t)d * NCHUNK + c) * 16 + n] = s;
        const float tot = cumdt[(size_t)(c * CLEN + CLEN - 1) * 2048 + d];
        s = s_end[((size_t)d * NCHUNK + c) * 16 + n] + __expf(Aa * tot) * s;
    }
}

// Pass C: z summed from 2 xz partials.
__global__ void scan_c_kernel(const float* __restrict__ u,
                              const float* __restrict__ xdbl,
                              const float* __restrict__ A_log,
                              const float* __restrict__ Dv,
                              const float* __restrict__ xz,
                              const float* __restrict__ cumdt,
                              const float* __restrict__ s_in,
                              ushort* __restrict__ yb) {
    const int idx = blockIdx.x * 256 + threadIdx.x;   // l*2048+d
    const int l = idx >> 11;
    const int d = idx & 2047;
    const int c = l >> 5;   // CLEN=32

    const float cd = cumdt[idx];
    const float ul = u[idx];
    const float yv = xz[(size_t)l * 4096 + d];
    const float zv = xz[(size_t)l * 4096 + 2048 + d]
                   + xz[(size_t)SEQ_L * 4096 + (size_t)l * 4096 + 2048 + d];
    const float* Cp = xdbl + (size_t)l * 96 + 80;
    const float* si = s_in + ((size_t)d * NCHUNK + c) * 16;

    float corr = 0.0f;
    #pragma unroll
    for (int q = 0; q < 4; ++q) {
        float4 al = *(const float4*)(A_log + (size_t)d * 16 + q * 4);
        float4 cv = *(const float4*)(Cp + q * 4);
        float4 sv = *(const float4*)(si + q * 4);
        corr = fmaf(cv.x * __expf(-__expf(al.x) * cd), sv.x, corr);
        corr = fmaf(cv.y * __expf(-__expf(al.y) * cd), sv.y, corr);
        corr = fmaf(cv.z * __expf(-__expf(al.z) * cd), sv.z, corr);
        corr = fmaf(cv.w * __expf(-__expf(al.w) * cd), sv.w, corr);
    }
    const float y = (yv + corr + Dv[d] * ul) * silu_f(zv);
    yb[idx] = f2bf(y);
}

extern "C" void kernel_launch(void* const* d_in, const int* in_sizes, int n_in,
                              void* d_out, int out_size, void* d_ws, size_t ws_size,
                              hipStream_t stream) {
    const int*   ids        = (const int*)d_in[0];
    const float* emb        = (const float*)d_in[1];
    const float* norm_w     = (const float*)d_in[2];
    const float* in_proj_w  = (const float*)d_in[3];
    const float* conv_w     = (const float*)d_in[4];
    const float* conv_b     = (const float*)d_in[5];
    const float* x_proj_w   = (const float*)d_in[6];
    const float* dt_proj_w  = (const float*)d_in[7];
    const float* dt_proj_b  = (const float*)d_in[8];
    const float* A_log      = (const float*)d_in[9];
    const float* Dv         = (const float*)d_in[10];
    const float* out_proj_w = (const float*)d_in[11];
    const float* norm_f_w   = (const float*)d_in[12];
    float* out = (float*)d_out;

    // ---- workspace layout ----
    char* p = (char*)d_ws;
    ushort* emb_b  = (ushort*)p; p += (size_t)VOCAB_PAD * D_MODEL * 2;      // 103 MB
    ushort* inw_b  = (ushort*)p; p += (size_t)N_LAYER * 4096 * 1024 * 2;    // 33.6 MB
    ushort* outw_b = (ushort*)p; p += (size_t)N_LAYER * 1024 * 2048 * 2;    // 16.8 MB
    ushort* xpw_b  = (ushort*)p; p += (size_t)N_LAYER * 128 * 2048 * 2;     //  2.1 MB (padded)
    ushort* dtw_b  = (ushort*)p; p += (size_t)N_LAYER * 2048 * 64 * 2;      //  1.0 MB
    float* residual = (float*)p; p += (size_t)SEQ_L * D_MODEL * 4;
    float* hpart    = (float*)p; p += (size_t)8 * SEQ_L * D_MODEL * 4;      // 33.6 MB (8 partials)
    float* scratch  = (float*)p; p += (size_t)2 * SEQ_L * 2048 * 4;         // 16.8 MB (xdpart/dtpart)
    float* xdbl     = (float*)p; p += (size_t)SEQ_L * 96 * 4;
    ushort* dtr_b   = (ushort*)p; p += (size_t)SEQ_L * 64 * 2;              //  0.13 MB
    ushort* xb      = (ushort*)p; p += (size_t)SEQ_L * D_MODEL * 2;
    float* xzp      = (float*)p; p += (size_t)2 * SEQ_L * 4096 * 4;         // 33.6 MB (2 partials)
    float* u        = (float*)p; p += (size_t)SEQ_L * 2048 * 4;
    ushort* u_b     = (ushort*)p; p += (size_t)SEQ_L * 2048 * 2;
    ushort* yb      = (ushort*)p; p += (size_t)SEQ_L * 2048 * 2;
    float* cumdt    = (float*)p; p += (size_t)SEQ_L * 2048 * 4;
    float* s_end    = (float*)p; p += (size_t)D_INNER * NCHUNK * 16 * 4;
    float* s_in     = (float*)p; p += (size_t)D_INNER * NCHUNK * 16 * 4;

    dim3 blk(256);

    // ---- weight conversions (once per launch) ----
    f32_to_bf16_kernel<<<dim3(VOCAB * D_MODEL / 4 / 256), blk, 0, stream>>>(
        emb, emb_b, VOCAB * D_MODEL / 4);
    f32_to_bf16_kernel<<<dim3(N_LAYER * 4096 * 1024 / 4 / 256), blk, 0, stream>>>(
        in_proj_w, inw_b, N_LAYER * 4096 * 1024 / 4);
    f32_to_bf16_kernel<<<dim3(N_LAYER * 1024 * 2048 / 4 / 256), blk, 0, stream>>>(
        out_proj_w, outw_b, N_LAYER * 1024 * 2048 / 4);
    f32_to_bf16_kernel<<<dim3(N_LAYER * 2048 * 64 / 4 / 256), blk, 0, stream>>>(
        dt_proj_w, dtw_b, N_LAYER * 2048 * 64 / 4);
    xpw_convert_kernel<<<dim3(N_LAYER * 128 * 2048 / 4 / 256), blk, 0, stream>>>(
        x_proj_w, xpw_b);

    // hidden lives in hpart slot 0 before layer 0
    embed_kernel<<<dim3(SEQ_L), blk, 0, stream>>>(ids, emb, hpart);

    for (int i = 0; i < N_LAYER; ++i) {
        // residual (+)= sum(partials) ; x = rmsnorm(residual)
        add_rmsnorm_kernel<<<dim3(SEQ_L), blk, 0, stream>>>(
            residual, hpart, norm_w + (size_t)i * D_MODEL, xb,
            i == 0 ? 0 : 1, i == 0 ? 1 : 8);

        // xz partials = x @ in_proj^T : M=1024 N=4096 K=1024
        // (NB=32, MB=8, KS=2 -> 512 blocks)
        gemm_bf16_gld_kernel<1><<<dim3(512), blk, 0, stream>>>(
            xb, inw_b + (size_t)i * 4096 * 1024, xzp, 4096, 1024, 1024, 4096,
            8, 2, SEQ_L * 4096);

        conv_silu_kernel<<<dim3(SEQ_L * D_INNER / 256), blk, 0, stream>>>(
            xzp, conv_w + (size_t)i * D_INNER * D_CONV, conv_b + (size_t)i * D_INNER,
            u, u_b);

        // xdbl partials: M=1024 N=96 K=2048 (NB=1, MB=8, KS=32 -> 256 blocks)
        gemm_bf16_gld_kernel<1><<<dim3(256), blk, 0, stream>>>(
            u_b, xpw_b + (size_t)i * 128 * 2048, scratch, 96, 2048, 2048, 96,
            8, 32, SEQ_L * 96);
        xdbl_reduce_kernel<<<dim3(SEQ_L * 96 / 4 / 256), blk, 0, stream>>>(
            scratch, xdbl, dtr_b);

        // dt pre-activation partials: M=1024 N=2048 K=64
        // (NB=16, MB=8, KS=2 -> 256 blocks); softplus+bias folded into scan_a
        gemm_bf16_gld_kernel<1><<<dim3(256), blk, 0, stream>>>(
            dtr_b, dtw_b + (size_t)i * 2048 * 64, scratch, 2048, 64, 64, 2048,
            8, 2, SEQ_L * 2048);

        // chunked scan
        scan_a_kernel<<<dim3(D_INNER * NCHUNK / 256), blk, 0, stream>>>(
            u, scratch, dt_proj_b + (size_t)i * D_INNER, xdbl,
            A_log + (size_t)i * D_INNER * D_STATE, xzp, cumdt, s_end);
        scan_b_kernel<<<dim3(D_INNER * 16 / 256), blk, 0, stream>>>(
            s_end, cumdt, A_log + (size_t)i * D_INNER * D_STATE, s_in);
        scan_c_kernel<<<dim3(SEQ_L * D_INNER / 256), blk, 0, stream>>>(
            u, xdbl, A_log + (size_t)i * D_INNER * D_STATE,
            Dv + (size_t)i * D_INNER, xzp, cumdt, s_in, yb);

        // hidden partials = y @ out_proj^T : M=1024 N=1024 K=2048
        // (NB=8, MB=8, KS=8 -> 512 blocks)
        gemm_bf16_gld_kernel<1><<<dim3(512), blk, 0, stream>>>(
            yb, outw_b + (size_t)i * 1024 * 2048, hpart, 1024, 2048, 2048, 1024,
            8, 8, SEQ_L * D_MODEL);
    }

    add_rmsnorm_kernel<<<dim3(SEQ_L), blk, 0, stream>>>(
        residual, hpart, norm_f_w, xb, 1, 8);

    // logits = hf @ emb^T : M=1024 N=50280 K=1024 (NB=393, MB=8 -> 3144 blocks)
    gemm_bf16_gld_kernel<0><<<dim3(3144), blk, 0, stream>>>(
        xb, emb_b, out, VOCAB, 1024, 1024, VOCAB, 8, 1, 0);
}

// Round 9
// 835.054 us; speedup vs baseline: 1.0049x; 1.0049x over previous
//
#include <hip/hip_runtime.h>
#include <hip/hip_bf16.h>

#define D_MODEL 1024
#define N_LAYER 4
#define D_INNER 2048
#define D_STATE 16
#define D_CONV  4
#define DT_RANK 64
#define SEQ_L   1024
#define VOCAB   50280
#define VOCAB_PAD 50432   // 197*256 (8-phase LM-head N padding)
#define NCHUNK  32
#define CLEN    32

typedef __attribute__((ext_vector_type(8))) short short8;
typedef __attribute__((ext_vector_type(4))) float f32x4;

typedef __attribute__((address_space(1))) const unsigned GUint;
typedef __attribute__((address_space(3))) unsigned LUint;

__device__ __forceinline__ float silu_f(float x) {
    return x / (1.0f + __expf(-x));
}
__device__ __forceinline__ float softplus_f(float x) {
    return fmaxf(x, 0.0f) + log1pf(__expf(-fabsf(x)));
}
__device__ __forceinline__ ushort f2bf(float f) {
    union { float f; unsigned u; } uf; uf.f = f;
    unsigned r = uf.u + 0x7FFF + ((uf.u >> 16) & 1);   // RNE
    return (ushort)(r >> 16);
}

// ---------------- fp32 -> bf16 bulk convert ----------------
__global__ void f32_to_bf16_kernel(const float* __restrict__ in,
                                   ushort* __restrict__ out, int n4) {
    int i = blockIdx.x * 256 + threadIdx.x;
    if (i >= n4) return;
    float4 v = *(const float4*)(in + (size_t)i * 4);
    ushort4 o;
    o.x = f2bf(v.x); o.y = f2bf(v.y); o.z = f2bf(v.z); o.w = f2bf(v.w);
    *(ushort4*)(out + (size_t)i * 4) = o;
}

// x_proj weights: (4,96,2048) fp32 -> (4,128,2048) bf16 with zero-filled pad rows
__global__ void xpw_convert_kernel(const float* __restrict__ src,
                                   ushort* __restrict__ dst) {
    int q = blockIdx.x * 256 + threadIdx.x;   // quad index, total 4*128*512
    int layer = q / (128 * 512);
    int rq    = q % (128 * 512);
    int row   = rq / 512;
    int cq    = rq % 512;
    ushort4 o;
    if (row < 96) {
        float4 v = *(const float4*)(src + ((size_t)layer * 96 + row) * 2048 + cq * 4);
        o.x = f2bf(v.x); o.y = f2bf(v.y); o.z = f2bf(v.z); o.w = f2bf(v.w);
    } else {
        o.x = o.y = o.z = o.w = 0;
    }
    *(ushort4*)(dst + (size_t)q * 4) = o;
}

// ---------------- embedding gather ----------------
__global__ void embed_kernel(const int* __restrict__ ids,
                             const float* __restrict__ emb,
                             float* __restrict__ hidden) {
    int l = blockIdx.x;
    int t = threadIdx.x;
    int id = ids[l];
    float4 v = *(const float4*)(emb + (size_t)id * D_MODEL + t * 4);
    *(float4*)(hidden + (size_t)l * D_MODEL + t * 4) = v;
}

// ---------------- residual add + RMSNorm -> bf16 x ----------------
__global__ void add_rmsnorm_kernel(float* __restrict__ res,
                                   const float* __restrict__ part,
                                   const float* __restrict__ w,
                                   ushort* __restrict__ xout,
                                   int add, int nparts) {
    int l = blockIdx.x;
    int t = threadIdx.x;
    size_t base = (size_t)l * D_MODEL + t * 4;
    float4 r;
    if (add) r = *(const float4*)(res + base);
    else     r = make_float4(0.f, 0.f, 0.f, 0.f);
    for (int s = 0; s < nparts; ++s) {
        float4 hv = *(const float4*)(part + (size_t)s * SEQ_L * D_MODEL + base);
        r.x += hv.x; r.y += hv.y; r.z += hv.z; r.w += hv.w;
    }
    *(float4*)(res + base) = r;
    float ss = r.x * r.x + r.y * r.y + r.z * r.z + r.w * r.w;
    #pragma unroll
    for (int off = 32; off > 0; off >>= 1) ss += __shfl_down(ss, off, 64);
    __shared__ float sred[4];
    if ((t & 63) == 0) sred[t >> 6] = ss;
    __syncthreads();
    float tot = sred[0] + sred[1] + sred[2] + sred[3];
    float scale = rsqrtf(tot * (1.0f / (float)D_MODEL) + 1e-5f);
    float4 wv = *(const float4*)(w + t * 4);
    ushort4 o;
    o.x = f2bf(r.x * scale * wv.x);
    o.y = f2bf(r.y * scale * wv.y);
    o.z = f2bf(r.z * scale * wv.z);
    o.w = f2bf(r.w * scale * wv.w);
    *(ushort4*)(xout + base) = o;
}

// ---------------- bf16 MFMA TN GEMM, global_load_lds staging (2-phase) ----------
// 128x128 tile, 4 waves, linear LDS, double-buffered, 1 barrier/K-step.
// Source-chunk pre-swizzle + matching read XOR -> 0 bank conflicts.
// SPLIT=1: K-split partial outputs to C + ks*pstride (non-atomic).
template<int SPLIT>
__global__ void gemm_bf16_gld_kernel(const ushort* __restrict__ A,
                                     const ushort* __restrict__ W,
                                     float* __restrict__ C,
                                     int N, int K, int lda, int ldc,
                                     int MB, int KS, int pstride) {
    __shared__ ushort As[2][128][32];
    __shared__ ushort Ws[2][128][32];
    const int t  = threadIdx.x;
    const int T  = gridDim.x >> 3;
    const int id = blockIdx.x;
    const int j  = (id & 7) * T + (id >> 3);
    const int ks  = j % KS;
    const int rem = j / KS;
    const int m0 = (rem % MB) * 128;
    const int n0 = (rem / MB) * 128;
    const int kchunk = K / KS;
    const int kbeg = ks * kchunk;
    const int kend = kbeg + kchunk;

    const int lane = t & 63;
    const int w    = t >> 6;                 // wave 0..3
    const int srow = w * 16 + (lane >> 2);
    const int scol = (((lane & 3) ^ ((lane >> 3) & 3)) * 8);   // swizzled src chunk
    const ushort* Ag0 = A + (size_t)(m0 + srow) * lda + scol;
    const ushort* Ag1 = A + (size_t)(m0 + srow + 64) * lda + scol;
    const ushort* Wg0 = W + (size_t)(n0 + srow) * K + scol;
    const ushort* Wg1 = W + (size_t)(n0 + srow + 64) * K + scol;

    const int wm = (t >> 7) & 1;
    const int wn = (t >> 6) & 1;
    const int lr = lane & 15;
    const int lk = lane >> 4;
    const int swz = (lr >> 1) & 3;           // read-side XOR pattern

    f32x4 acc[4][4] = {};

#define STAGE_GLD(buf, kk)                                                        \
    do {                                                                          \
        __builtin_amdgcn_global_load_lds((GUint*)(Ag0 + (kk)),                    \
            (LUint*)&As[buf][w * 16][0], 16, 0, 0);                               \
        __builtin_amdgcn_global_load_lds((GUint*)(Ag1 + (kk)),                    \
            (LUint*)&As[buf][64 + w * 16][0], 16, 0, 0);                          \
        __builtin_amdgcn_global_load_lds((GUint*)(Wg0 + (kk)),                    \
            (LUint*)&Ws[buf][w * 16][0], 16, 0, 0);                               \
        __builtin_amdgcn_global_load_lds((GUint*)(Wg1 + (kk)),                    \
            (LUint*)&Ws[buf][64 + w * 16][0], 16, 0, 0);                          \
    } while (0)

    STAGE_GLD(0, kbeg);
    int buf = 0;
    for (int k0 = kbeg;;) {
        __syncthreads();
        const bool more = (k0 + 32) < kend;
        if (more) STAGE_GLD(buf ^ 1, k0 + 32);

        short8 af[4], bfr[4];
        #pragma unroll
        for (int m = 0; m < 4; ++m)
            af[m] = *(const short8*)&As[buf][wm * 64 + m * 16 + lr][(lk ^ swz) * 8];
        #pragma unroll
        for (int n = 0; n < 4; ++n)
            bfr[n] = *(const short8*)&Ws[buf][wn * 64 + n * 16 + lr][(lk ^ swz) * 8];
        #pragma unroll
        for (int m = 0; m < 4; ++m)
            #pragma unroll
            for (int n = 0; n < 4; ++n)
                acc[m][n] = __builtin_amdgcn_mfma_f32_16x16x32_bf16(
                    af[m], bfr[n], acc[m][n], 0, 0, 0);

        if (!more) break;
        buf ^= 1;
        k0 += 32;
    }
#undef STAGE_GLD

    float* Cp = SPLIT ? (C + (size_t)ks * pstride) : C;
    #pragma unroll
    for (int m = 0; m < 4; ++m) {
        const int row = m0 + wm * 64 + m * 16 + lk * 4;
        #pragma unroll
        for (int n = 0; n < 4; ++n) {
            const int col = n0 + wn * 64 + n * 16 + lr;
            if (col < N) {
                #pragma unroll
                for (int r = 0; r < 4; ++r)
                    Cp[(size_t)(row + r) * ldc + col] = acc[m][n][r];
            }
        }
    }
}

// ---------------- bf16 MFMA TN GEMM, 256x256 deep-pipelined (T3+T4) ----------
// 512 threads / 8 waves (2M x 4N), BK=32, 4-deep LDS ring (128 KB), prefetch
// distance 2 tiles, counted s_waitcnt vmcnt(4) + raw s_barrier per tile
// (loads stay in flight across barriers). XOR-swizzled LDS via pre-swizzled
// global source (rule #21): write chunk (l&3)^((l>>3)&3), read XOR lk^((lr>>1)&3).
// Requires M % 256 == 0, K % 32 == 0, K/32 >= 2; W rows readable to padded N.
__global__ __launch_bounds__(512)
void gemm_bf16_8ph_kernel(const ushort* __restrict__ A,
                          const ushort* __restrict__ W,
                          float* __restrict__ C,
                          int N, int K, int lda, int ldc, int MB) {
    __shared__ ushort As[4][256][32];
    __shared__ ushort Bs[4][256][32];
    const int t    = threadIdx.x;
    const int lane = t & 63;
    const int w    = t >> 6;                  // wave 0..7

    // bijective XCD swizzle (m204): works for any gridDim
    const int nwg = gridDim.x;
    const int q = nwg >> 3, r = nwg & 7;
    const int xcd = blockIdx.x & 7, pos = blockIdx.x >> 3;
    const int j = (xcd < r ? xcd * (q + 1) : r * (q + 1) + (xcd - r) * q) + pos;
    const int m0 = (j % MB) * 256;
    const int n0 = (j / MB) * 256;

    // staging decode: per instr, wave w writes 16 rows x 64B (1 KB linear)
    const int srow = (w << 4) + (lane >> 2);                   // 0..127 per half
    const int scol = (((lane & 3) ^ ((lane >> 3) & 3)) << 3);  // swizzled elems
    const ushort* Ag = A + (size_t)(m0 + srow) * lda + scol;
    const ushort* Wg = W + (size_t)(n0 + srow) * K + scol;

    // compute decode
    const int wm = w >> 2;        // 0..1 -> 128-row half
    const int wn = w & 3;         // 0..3 -> 64-col quarter
    const int lr = lane & 15;
    const int lk = lane >> 4;
    const int rsw = ((lk ^ ((lr >> 1) & 3)) << 3);  // physical col (elems)

    f32x4 acc[8][4] = {};
    const int NT = K >> 5;

#define STG_A(buf, half, kk)                                                     \
    __builtin_amdgcn_global_load_lds(                                           \
        (GUint*)(Ag + (size_t)(half) * 128 * lda + (kk)),                        \
        (LUint*)&As[buf][(half) * 128 + (w << 4)][0], 16, 0, 0)
#define STG_B(buf, half, kk)                                                     \
    __builtin_amdgcn_global_load_lds(                                           \
        (GUint*)(Wg + (size_t)(half) * 128 * K + (kk)),                          \
        (LUint*)&Bs[buf][(half) * 128 + (w << 4)][0], 16, 0, 0)

    // prologue: stage tiles 0 and 1 (8 loads), wait for tile 0 (4 left in flight)
    STG_A(0, 0, 0);  STG_A(0, 1, 0);  STG_B(0, 0, 0);  STG_B(0, 1, 0);
    STG_A(1, 0, 32); STG_A(1, 1, 32); STG_B(1, 0, 32); STG_B(1, 1, 32);
    asm volatile("s_waitcnt vmcnt(4)" ::: "memory");
    __builtin_amdgcn_s_barrier();
    __builtin_amdgcn_sched_barrier(0);

    for (int tt = 0; tt < NT; ++tt) {
        const int buf  = tt & 3;
        const bool pf  = (tt + 2) < NT;
        const int pbuf = (tt + 2) & 3;
        const int pk   = (tt + 2) << 5;

        short8 a[4], b[4];

        // ---- phase 0: stage A-halves of tile t+2; compute m0..3 x n0..3 ----
        if (pf) { STG_A(pbuf, 0, pk); STG_A(pbuf, 1, pk); }
        #pragma unroll
        for (int m = 0; m < 4; ++m)
            a[m] = *(const short8*)&As[buf][wm * 128 + m * 16 + lr][rsw];
        #pragma unroll
        for (int n = 0; n < 4; ++n)
            b[n] = *(const short8*)&Bs[buf][wn * 64 + n * 16 + lr][rsw];
        __builtin_amdgcn_s_setprio(1);
        #pragma unroll
        for (int m = 0; m < 4; ++m)
            #pragma unroll
            for (int n = 0; n < 4; ++n)
                acc[m][n] = __builtin_amdgcn_mfma_f32_16x16x32_bf16(
                    a[m], b[n], acc[m][n], 0, 0, 0);
        __builtin_amdgcn_s_setprio(0);

        // ---- phase 1: stage B-halves of tile t+2; compute m4..7 x n0..3 ----
        if (pf) { STG_B(pbuf, 0, pk); STG_B(pbuf, 1, pk); }
        #pragma unroll
        for (int m = 0; m < 4; ++m)
            a[m] = *(const short8*)&As[buf][wm * 128 + (m + 4) * 16 + lr][rsw];
        __builtin_amdgcn_s_setprio(1);
        #pragma unroll
        for (int m = 0; m < 4; ++m)
            #pragma unroll
            for (int n = 0; n < 4; ++n)
                acc[m + 4][n] = __builtin_amdgcn_mfma_f32_16x16x32_bf16(
                    a[m], b[n], acc[m + 4][n], 0, 0, 0);
        __builtin_amdgcn_s_setprio(0);

        // ---- tile boundary: counted wait (never drain mid-loop) ----
        if (tt + 1 < NT) {
            if (pf) asm volatile("s_waitcnt vmcnt(4)" ::: "memory");
            else    asm volatile("s_waitcnt vmcnt(0)" ::: "memory");
            __builtin_amdgcn_s_barrier();
            __builtin_amdgcn_sched_barrier(0);
        }
    }
#undef STG_A
#undef STG_B

    // epilogue: C row = m0+wm*128+m*16+lk*4+r, col = n0+wn*64+n*16+lr
    #pragma unroll
    for (int m = 0; m < 8; ++m) {
        const int row = m0 + wm * 128 + m * 16 + lk * 4;
        #pragma unroll
        for (int n = 0; n < 4; ++n) {
            const int col = n0 + wn * 64 + n * 16 + lr;
            if (col < N) {
                #pragma unroll
                for (int rr = 0; rr < 4; ++rr)
                    C[(size_t)(row + rr) * ldc + col] = acc[m][n][rr];
            }
        }
    }
}

// ---------------- xdbl 16-partial reduce ----------------
__global__ void xdbl_reduce_kernel(const float* __restrict__ part,
                                   float* __restrict__ out) {
    int i = blockIdx.x * 256 + threadIdx.x;   // quad index, 24576 total
    float4 acc = make_float4(0.f, 0.f, 0.f, 0.f);
    #pragma unroll
    for (int s = 0; s < 16; ++s) {
        float4 v = *(const float4*)(part + (size_t)s * SEQ_L * 96 + (size_t)i * 4);
        acc.x += v.x; acc.y += v.y; acc.z += v.z; acc.w += v.w;
    }
    *(float4*)(out + (size_t)i * 4) = acc;
}

// ---------------- fp32 TN GEMM (dt_proj only) ----------------
template<int EPI>
__global__ void gemm_tn_kernel(const float* __restrict__ A,
                               const float* __restrict__ W,
                               const float* __restrict__ bias,
                               float* __restrict__ C,
                               int M, int N, int K, int lda) {
    __shared__ float As[16][68];
    __shared__ float Ws[16][68];
    const int t  = threadIdx.x;
    const int m0 = blockIdx.y * 64;
    const int n0 = blockIdx.x * 64;
    const int lrow = t >> 2;
    const int lkq  = (t & 3) * 4;
    const int tx = t & 15;
    const int ty = t >> 4;

    const float* Arow = A + (size_t)(m0 + lrow) * lda;
    const int   wr    = n0 + lrow;
    const bool  wvalid = wr < N;
    const float* Wrow = W + (size_t)(wvalid ? wr : 0) * K;

    float acc[4][4] = {};
    for (int k0 = 0; k0 < K; k0 += 16) {
        float4 av = *(const float4*)(Arow + k0 + lkq);
        float4 wv = wvalid ? *(const float4*)(Wrow + k0 + lkq)
                           : make_float4(0.f, 0.f, 0.f, 0.f);
        As[lkq + 0][lrow] = av.x; As[lkq + 1][lrow] = av.y;
        As[lkq + 2][lrow] = av.z; As[lkq + 3][lrow] = av.w;
        Ws[lkq + 0][lrow] = wv.x; Ws[lkq + 1][lrow] = wv.y;
        Ws[lkq + 2][lrow] = wv.z; Ws[lkq + 3][lrow] = wv.w;
        __syncthreads();
        #pragma unroll
        for (int kk = 0; kk < 16; ++kk) {
            float4 a = *(const float4*)&As[kk][ty * 4];
            float4 b = *(const float4*)&Ws[kk][tx * 4];
            #pragma unroll
            for (int i = 0; i < 4; ++i) {
                float ai = (i == 0) ? a.x : (i == 1) ? a.y : (i == 2) ? a.z : a.w;
                acc[i][0] = fmaf(ai, b.x, acc[i][0]);
                acc[i][1] = fmaf(ai, b.y, acc[i][1]);
                acc[i][2] = fmaf(ai, b.z, acc[i][2]);
                acc[i][3] = fmaf(ai, b.w, acc[i][3]);
            }
        }
        __syncthreads();
    }

    const int colb = n0 + tx * 4;
    if (colb < N) {
        #pragma unroll
        for (int i = 0; i < 4; ++i) {
            int row = m0 + ty * 4 + i;
            float4 v = make_float4(acc[i][0], acc[i][1], acc[i][2], acc[i][3]);
            if (EPI == 1) {
                v.x = softplus_f(v.x + bias[colb + 0]);
                v.y = softplus_f(v.y + bias[colb + 1]);
                v.z = softplus_f(v.z + bias[colb + 2]);
                v.w = softplus_f(v.w + bias[colb + 3]);
            }
            *(float4*)(C + (size_t)row * N + colb) = v;
        }
    }
}

// ---------------- depthwise causal conv (k=4) + silu ----------------
__global__ void conv_silu_kernel(const float* __restrict__ xz,
                                 const float* __restrict__ cw,
                                 const float* __restrict__ cb,
                                 float* __restrict__ u,
                                 ushort* __restrict__ u_b) {
    int idx = blockIdx.x * 256 + threadIdx.x;
    int l = idx >> 11;
    int c = idx & 2047;
    float acc = cb[c];
    float w0 = cw[c * 4 + 0], w1 = cw[c * 4 + 1], w2 = cw[c * 4 + 2], w3 = cw[c * 4 + 3];
    if (l >= 3) acc = fmaf(xz[(size_t)(l - 3) * 4096 + c], w0, acc);
    if (l >= 2) acc = fmaf(xz[(size_t)(l - 2) * 4096 + c], w1, acc);
    if (l >= 1) acc = fmaf(xz[(size_t)(l - 1) * 4096 + c], w2, acc);
    acc = fmaf(xz[(size_t)l * 4096 + c], w3, acc);
    float s = silu_f(acc);
    u[idx] = s;
    u_b[idx] = f2bf(s);
}

// ---------------- chunked selective scan ----------------
__global__ void scan_a_kernel(const float* __restrict__ u,
                              const float* __restrict__ dt,
                              const float* __restrict__ xdbl,
                              const float* __restrict__ A_log,
                              float* __restrict__ yloc,
                              float* __restrict__ cumdt,
                              float* __restrict__ s_end) {
    const int idx = blockIdx.x * 256 + threadIdx.x;   // 65536
    const int d = idx & 2047;
    const int c = idx >> 11;

    float Aa[16];
    #pragma unroll
    for (int q = 0; q < 4; ++q) {
        float4 al = *(const float4*)(A_log + (size_t)d * 16 + q * 4);
        Aa[q * 4 + 0] = -__expf(al.x);
        Aa[q * 4 + 1] = -__expf(al.y);
        Aa[q * 4 + 2] = -__expf(al.z);
        Aa[q * 4 + 3] = -__expf(al.w);
    }

    float s[16];
    #pragma unroll
    for (int n = 0; n < 16; ++n) s[n] = 0.0f;
    float cd = 0.0f;

    const int l0 = c * CLEN;
    for (int i = 0; i < CLEN; ++i) {
        const int l = l0 + i;
        const float dtl = dt[(size_t)l * 2048 + d];
        const float ul  = u[(size_t)l * 2048 + d];
        float Bn[16], Cn[16];
        const float* xbp = xdbl + (size_t)l * 96;
        *(float4*)&Bn[0]  = *(const float4*)(xbp + 64);
        *(float4*)&Bn[4]  = *(const float4*)(xbp + 68);
        *(float4*)&Bn[8]  = *(const float4*)(xbp + 72);
        *(float4*)&Bn[12] = *(const float4*)(xbp + 76);
        *(float4*)&Cn[0]  = *(const float4*)(xbp + 80);
        *(float4*)&Cn[4]  = *(const float4*)(xbp + 84);
        *(float4*)&Cn[8]  = *(const float4*)(xbp + 88);
        *(float4*)&Cn[12] = *(const float4*)(xbp + 92);
        cd += dtl;
        const float dtu = dtl * ul;
        float y = 0.0f;
        #pragma unroll
        for (int n = 0; n < 16; ++n) {
            float dA = __expf(dtl * Aa[n]);
            s[n] = fmaf(s[n], dA, dtu * Bn[n]);
            y = fmaf(s[n], Cn[n], y);
        }
        yloc[(size_t)l * 4096 + d] = y;
        cumdt[(size_t)l * 2048 + d] = cd;
    }
    float* se = s_end + ((size_t)d * NCHUNK + c) * 16;
    #pragma unroll
    for (int q = 0; q < 4; ++q)
        *(float4*)(se + q * 4) = make_float4(s[q * 4], s[q * 4 + 1], s[q * 4 + 2], s[q * 4 + 3]);
}

__global__ void scan_b_kernel(const float* __restrict__ s_end,
                              const float* __restrict__ cumdt,
                              const float* __restrict__ A_log,
                              float* __restrict__ s_in) {
    const int idx = blockIdx.x * 256 + threadIdx.x;   // 32768
    const int d = idx >> 4;
    const int n = idx & 15;
    const float Aa = -__expf(A_log[(size_t)d * 16 + n]);
    float s = 0.0f;
    #pragma unroll
    for (int c = 0; c < NCHUNK; ++c) {
        s_in[((size_t)d * NCHUNK + c) * 16 + n] = s;
        const float tot = cumdt[(size_t)(c * CLEN + CLEN - 1) * 2048 + d];
        s = s_end[((size_t)d * NCHUNK + c) * 16 + n] + __expf(Aa * tot) * s;
    }
}

__global__ void scan_c_kernel(const float* __restrict__ u,
                              const float* __restrict__ xdbl,
                              const float* __restrict__ A_log,
                              const float* __restrict__ Dv,
                              const float* __restrict__ xz,
                              const float* __restrict__ cumdt,
                              const float* __restrict__ s_in,
                              ushort* __restrict__ yb) {
    const int idx = blockIdx.x * 256 + threadIdx.x;   // l*2048+d
    const int l = idx >> 11;
    const int d = idx & 2047;
    const int c = l >> 5;   // CLEN=32

    const float cd = cumdt[idx];
    const float ul = u[idx];
    const float yv = xz[(size_t)l * 4096 + d];
    const float zv = xz[(size_t)l * 4096 + 2048 + d];
    const float* Cp = xdbl + (size_t)l * 96 + 80;
    const float* si = s_in + ((size_t)d * NCHUNK + c) * 16;

    float corr = 0.0f;
    #pragma unroll
    for (int q = 0; q < 4; ++q) {
        float4 al = *(const float4*)(A_log + (size_t)d * 16 + q * 4);
        float4 cv = *(const float4*)(Cp + q * 4);
        float4 sv = *(const float4*)(si + q * 4);
        corr = fmaf(cv.x * __expf(-__expf(al.x) * cd), sv.x, corr);
        corr = fmaf(cv.y * __expf(-__expf(al.y) * cd), sv.y, corr);
        corr = fmaf(cv.z * __expf(-__expf(al.z) * cd), sv.z, corr);
        corr = fmaf(cv.w * __expf(-__expf(al.w) * cd), sv.w, corr);
    }
    const float y = (yv + corr + Dv[d] * ul) * silu_f(zv);
    yb[idx] = f2bf(y);
}

extern "C" void kernel_launch(void* const* d_in, const int* in_sizes, int n_in,
                              void* d_out, int out_size, void* d_ws, size_t ws_size,
                              hipStream_t stream) {
    const int*   ids        = (const int*)d_in[0];
    const float* emb        = (const float*)d_in[1];
    const float* norm_w     = (const float*)d_in[2];
    const float* in_proj_w  = (const float*)d_in[3];
    const float* conv_w     = (const float*)d_in[4];
    const float* conv_b     = (const float*)d_in[5];
    const float* x_proj_w   = (const float*)d_in[6];
    const float* dt_proj_w  = (const float*)d_in[7];
    const float* dt_proj_b  = (const float*)d_in[8];
    const float* A_log      = (const float*)d_in[9];
    const float* Dv         = (const float*)d_in[10];
    const float* out_proj_w = (const float*)d_in[11];
    const float* norm_f_w   = (const float*)d_in[12];
    float* out = (float*)d_out;

    // ---- workspace layout (round-7 structure, emb padded to 50432 rows) ----
    char* p = (char*)d_ws;
    ushort* emb_b  = (ushort*)p; p += (size_t)VOCAB_PAD * D_MODEL * 2;      // 103 MB
    ushort* inw_b  = (ushort*)p; p += (size_t)N_LAYER * 4096 * 1024 * 2;    // 33.6 MB
    ushort* outw_b = (ushort*)p; p += (size_t)N_LAYER * 1024 * 2048 * 2;    // 16.8 MB
    ushort* xpw_b  = (ushort*)p; p += (size_t)N_LAYER * 128 * 2048 * 2;     //  2.1 MB
    float* residual = (float*)p; p += (size_t)SEQ_L * D_MODEL * 4;
    float* hpart    = (float*)p; p += (size_t)4 * SEQ_L * D_MODEL * 4;      // 16.8 MB
    float* xdpart   = (float*)p; p += (size_t)16 * SEQ_L * 96 * 4;          //  6.3 MB
    float* xdbl     = (float*)p; p += (size_t)SEQ_L * 96 * 4;
    ushort* xb      = (ushort*)p; p += (size_t)SEQ_L * D_MODEL * 2;
    float* xz       = (float*)p; p += (size_t)SEQ_L * 4096 * 4;
    float* u        = (float*)p; p += (size_t)SEQ_L * 2048 * 4;
    ushort* u_b     = (ushort*)p; p += (size_t)SEQ_L * 2048 * 2;
    float* dtb      = (float*)p; p += (size_t)SEQ_L * 2048 * 4;
    ushort* yb      = (ushort*)p; p += (size_t)SEQ_L * 2048 * 2;
    float* cumdt    = (float*)p; p += (size_t)SEQ_L * 2048 * 4;
    float* s_end    = (float*)p; p += (size_t)D_INNER * NCHUNK * 16 * 4;
    float* s_in     = (float*)p; p += (size_t)D_INNER * NCHUNK * 16 * 4;

    dim3 blk(256);

    // ---- weight conversions (once per launch) ----
    f32_to_bf16_kernel<<<dim3(VOCAB * D_MODEL / 4 / 256), blk, 0, stream>>>(
        emb, emb_b, VOCAB * D_MODEL / 4);
    f32_to_bf16_kernel<<<dim3(N_LAYER * 4096 * 1024 / 4 / 256), blk, 0, stream>>>(
        in_proj_w, inw_b, N_LAYER * 4096 * 1024 / 4);
    f32_to_bf16_kernel<<<dim3(N_LAYER * 1024 * 2048 / 4 / 256), blk, 0, stream>>>(
        out_proj_w, outw_b, N_LAYER * 1024 * 2048 / 4);
    xpw_convert_kernel<<<dim3(N_LAYER * 128 * 2048 / 4 / 256), blk, 0, stream>>>(
        x_proj_w, xpw_b);

    embed_kernel<<<dim3(SEQ_L), blk, 0, stream>>>(ids, emb, hpart);

    for (int i = 0; i < N_LAYER; ++i) {
        add_rmsnorm_kernel<<<dim3(SEQ_L), blk, 0, stream>>>(
            residual, hpart, norm_w + (size_t)i * D_MODEL, xb,
            i == 0 ? 0 : 1, i == 0 ? 1 : 4);

        // xz = x @ in_proj^T : M=1024 N=4096 K=1024 (NB=32, MB=8 -> 256 blocks)
        gemm_bf16_gld_kernel<0><<<dim3(256), blk, 0, stream>>>(
            xb, inw_b + (size_t)i * 4096 * 1024, xz, 4096, 1024, 1024, 4096, 8, 1, 0);

        conv_silu_kernel<<<dim3(SEQ_L * D_INNER / 256), blk, 0, stream>>>(
            xz, conv_w + (size_t)i * D_INNER * D_CONV, conv_b + (size_t)i * D_INNER,
            u, u_b);

        // xdbl partials: M=1024 N=96 K=2048 (NB=1, MB=8, KS=16 -> 128 blocks)
        gemm_bf16_gld_kernel<1><<<dim3(128), blk, 0, stream>>>(
            u_b, xpw_b + (size_t)i * 128 * 2048, xdpart, 96, 2048, 2048, 96,
            8, 16, SEQ_L * 96);
        xdbl_reduce_kernel<<<dim3(SEQ_L * 96 / 4 / 256), blk, 0, stream>>>(
            xdpart, xdbl);

        // dt = softplus(dt_r @ dt_proj^T + b)
        gemm_tn_kernel<1><<<dim3(D_INNER / 64, SEQ_L / 64), blk, 0, stream>>>(
            xdbl, dt_proj_w + (size_t)i * D_INNER * DT_RANK,
            dt_proj_b + (size_t)i * D_INNER, dtb,
            SEQ_L, D_INNER, DT_RANK, 96);

        // chunked scan
        scan_a_kernel<<<dim3(D_INNER * NCHUNK / 256), blk, 0, stream>>>(
            u, dtb, xdbl, A_log + (size_t)i * D_INNER * D_STATE, xz, cumdt, s_end);
        scan_b_kernel<<<dim3(D_INNER * 16 / 256), blk, 0, stream>>>(
            s_end, cumdt, A_log + (size_t)i * D_INNER * D_STATE, s_in);
        scan_c_kernel<<<dim3(SEQ_L * D_INNER / 256), blk, 0, stream>>>(
            u, xdbl, A_log + (size_t)i * D_INNER * D_STATE,
            Dv + (size_t)i * D_INNER, xz, cumdt, s_in, yb);

        // hidden partials = y @ out_proj^T : M=1024 N=1024 K=2048
        // (NB=8, MB=8, KS=4 -> 256 blocks), partial buffers, no atomics
        gemm_bf16_gld_kernel<1><<<dim3(256), blk, 0, stream>>>(
            yb, outw_b + (size_t)i * 1024 * 2048, hpart, 1024, 2048, 2048, 1024,
            8, 4, SEQ_L * D_MODEL);
    }

    add_rmsnorm_kernel<<<dim3(SEQ_L), blk, 0, stream>>>(
        residual, hpart, norm_f_w, xb, 1, 4);

    // logits = hf @ emb^T : M=1024 N=50280 K=1024
    // 256x256 deep-pipelined kernel: MB=4 M-tiles x 197 N-tiles = 788 blocks
    gemm_bf16_8ph_kernel<<<dim3(788), dim3(512), 0, stream>>>(
        xb, emb_b, out, VOCAB, 1024, 1024, VOCAB, 4);
}

// Round 10
// 822.186 us; speedup vs baseline: 1.0206x; 1.0157x over previous
//
#include <hip/hip_runtime.h>
#include <hip/hip_bf16.h>

#define D_MODEL 1024
#define N_LAYER 4
#define D_INNER 2048
#define D_STATE 16
#define D_CONV  4
#define DT_RANK 64
#define SEQ_L   1024
#define VOCAB   50280
#define VOCAB_PAD 50304   // 393*128
#define NCHUNK  64
#define CLEN    16

typedef __attribute__((ext_vector_type(8))) short short8;
typedef __attribute__((ext_vector_type(4))) float f32x4;

typedef __attribute__((address_space(1))) const unsigned GUint;
typedef __attribute__((address_space(3))) unsigned LUint;

__device__ __forceinline__ float silu_f(float x) {
    return x / (1.0f + __expf(-x));
}
__device__ __forceinline__ float softplus_f(float x) {
    return fmaxf(x, 0.0f) + log1pf(__expf(-fabsf(x)));
}
__device__ __forceinline__ ushort f2bf(float f) {
    union { float f; unsigned u; } uf; uf.f = f;
    unsigned r = uf.u + 0x7FFF + ((uf.u >> 16) & 1);   // RNE
    return (ushort)(r >> 16);
}

// ---------------- fp32 -> bf16 bulk convert ----------------
__global__ void f32_to_bf16_kernel(const float* __restrict__ in,
                                   ushort* __restrict__ out, int n4) {
    int i = blockIdx.x * 256 + threadIdx.x;
    if (i >= n4) return;
    float4 v = *(const float4*)(in + (size_t)i * 4);
    ushort4 o;
    o.x = f2bf(v.x); o.y = f2bf(v.y); o.z = f2bf(v.z); o.w = f2bf(v.w);
    *(ushort4*)(out + (size_t)i * 4) = o;
}

// x_proj weights: (4,96,2048) fp32 -> (4,128,2048) bf16 with zero-filled pad rows
__global__ void xpw_convert_kernel(const float* __restrict__ src,
                                   ushort* __restrict__ dst) {
    int q = blockIdx.x * 256 + threadIdx.x;   // quad index, total 4*128*512
    int layer = q / (128 * 512);
    int rq    = q % (128 * 512);
    int row   = rq / 512;
    int cq    = rq % 512;
    ushort4 o;
    if (row < 96) {
        float4 v = *(const float4*)(src + ((size_t)layer * 96 + row) * 2048 + cq * 4);
        o.x = f2bf(v.x); o.y = f2bf(v.y); o.z = f2bf(v.z); o.w = f2bf(v.w);
    } else {
        o.x = o.y = o.z = o.w = 0;
    }
    *(ushort4*)(dst + (size_t)q * 4) = o;
}

// ---------------- embedding gather ----------------
__global__ void embed_kernel(const int* __restrict__ ids,
                             const float* __restrict__ emb,
                             float* __restrict__ hidden) {
    int l = blockIdx.x;
    int t = threadIdx.x;
    int id = ids[l];
    float4 v = *(const float4*)(emb + (size_t)id * D_MODEL + t * 4);
    *(float4*)(hidden + (size_t)l * D_MODEL + t * 4) = v;
}

// ---------------- residual add + RMSNorm -> bf16 x ----------------
__global__ void add_rmsnorm_kernel(float* __restrict__ res,
                                   const float* __restrict__ part,
                                   const float* __restrict__ w,
                                   ushort* __restrict__ xout,
                                   int add, int nparts) {
    int l = blockIdx.x;
    int t = threadIdx.x;
    size_t base = (size_t)l * D_MODEL + t * 4;
    float4 r;
    if (add) r = *(const float4*)(res + base);
    else     r = make_float4(0.f, 0.f, 0.f, 0.f);
    for (int s = 0; s < nparts; ++s) {
        float4 hv = *(const float4*)(part + (size_t)s * SEQ_L * D_MODEL + base);
        r.x += hv.x; r.y += hv.y; r.z += hv.z; r.w += hv.w;
    }
    *(float4*)(res + base) = r;
    float ss = r.x * r.x + r.y * r.y + r.z * r.z + r.w * r.w;
    #pragma unroll
    for (int off = 32; off > 0; off >>= 1) ss += __shfl_down(ss, off, 64);
    __shared__ float sred[4];
    if ((t & 63) == 0) sred[t >> 6] = ss;
    __syncthreads();
    float tot = sred[0] + sred[1] + sred[2] + sred[3];
    float scale = rsqrtf(tot * (1.0f / (float)D_MODEL) + 1e-5f);
    float4 wv = *(const float4*)(w + t * 4);
    ushort4 o;
    o.x = f2bf(r.x * scale * wv.x);
    o.y = f2bf(r.y * scale * wv.y);
    o.z = f2bf(r.z * scale * wv.z);
    o.w = f2bf(r.w * scale * wv.w);
    *(ushort4*)(xout + base) = o;
}

// ---------------- bf16 MFMA TN GEMM, global_load_lds staging ----------------
// 128x128 tile, 4 waves, linear LDS, double-buffered, 1 barrier/K-step.
// Source-chunk pre-swizzle + matching read XOR -> 0 bank conflicts.
// SPLIT=1: K-split partial outputs to C + ks*pstride (non-atomic).
// EPI=1: C = softplus(acc + bias[col]) (dt_proj).
template<int SPLIT, int EPI>
__global__ void gemm_bf16_gld_kernel(const ushort* __restrict__ A,
                                     const ushort* __restrict__ W,
                                     float* __restrict__ C,
                                     const float* __restrict__ bias,
                                     int N, int K, int lda, int ldc,
                                     int MB, int KS, int pstride) {
    __shared__ ushort As[2][128][32];
    __shared__ ushort Ws[2][128][32];
    const int t  = threadIdx.x;
    const int T  = gridDim.x >> 3;
    const int id = blockIdx.x;
    const int j  = (id & 7) * T + (id >> 3);
    const int ks  = j % KS;
    const int rem = j / KS;
    const int m0 = (rem % MB) * 128;
    const int n0 = (rem / MB) * 128;
    const int kchunk = K / KS;
    const int kbeg = ks * kchunk;
    const int kend = kbeg + kchunk;

    const int lane = t & 63;
    const int w    = t >> 6;                 // wave 0..3
    const int srow = w * 16 + (lane >> 2);
    const int scol = (((lane & 3) ^ ((lane >> 3) & 3)) * 8);   // swizzled src chunk
    const ushort* Ag0 = A + (size_t)(m0 + srow) * lda + scol;
    const ushort* Ag1 = A + (size_t)(m0 + srow + 64) * lda + scol;
    const ushort* Wg0 = W + (size_t)(n0 + srow) * K + scol;
    const ushort* Wg1 = W + (size_t)(n0 + srow + 64) * K + scol;

    const int wm = (t >> 7) & 1;
    const int wn = (t >> 6) & 1;
    const int lr = lane & 15;
    const int lk = lane >> 4;
    const int swz = (lr >> 1) & 3;           // read-side XOR pattern

    f32x4 acc[4][4] = {};

#define STAGE_GLD(buf, kk)                                                        \
    do {                                                                          \
        __builtin_amdgcn_global_load_lds((GUint*)(Ag0 + (kk)),                    \
            (LUint*)&As[buf][w * 16][0], 16, 0, 0);                               \
        __builtin_amdgcn_global_load_lds((GUint*)(Ag1 + (kk)),                    \
            (LUint*)&As[buf][64 + w * 16][0], 16, 0, 0);                          \
        __builtin_amdgcn_global_load_lds((GUint*)(Wg0 + (kk)),                    \
            (LUint*)&Ws[buf][w * 16][0], 16, 0, 0);                               \
        __builtin_amdgcn_global_load_lds((GUint*)(Wg1 + (kk)),                    \
            (LUint*)&Ws[buf][64 + w * 16][0], 16, 0, 0);                          \
    } while (0)

    STAGE_GLD(0, kbeg);
    int buf = 0;
    for (int k0 = kbeg;;) {
        __syncthreads();
        const bool more = (k0 + 32) < kend;
        if (more) STAGE_GLD(buf ^ 1, k0 + 32);

        short8 af[4], bfr[4];
        #pragma unroll
        for (int m = 0; m < 4; ++m)
            af[m] = *(const short8*)&As[buf][wm * 64 + m * 16 + lr][(lk ^ swz) * 8];
        #pragma unroll
        for (int n = 0; n < 4; ++n)
            bfr[n] = *(const short8*)&Ws[buf][wn * 64 + n * 16 + lr][(lk ^ swz) * 8];
        #pragma unroll
        for (int m = 0; m < 4; ++m)
            #pragma unroll
            for (int n = 0; n < 4; ++n)
                acc[m][n] = __builtin_amdgcn_mfma_f32_16x16x32_bf16(
                    af[m], bfr[n], acc[m][n], 0, 0, 0);

        if (!more) break;
        buf ^= 1;
        k0 += 32;
    }
#undef STAGE_GLD

    float* Cp = SPLIT ? (C + (size_t)ks * pstride) : C;
    #pragma unroll
    for (int m = 0; m < 4; ++m) {
        const int row = m0 + wm * 64 + m * 16 + lk * 4;
        #pragma unroll
        for (int n = 0; n < 4; ++n) {
            const int col = n0 + wn * 64 + n * 16 + lr;
            if (col < N) {
                const float bv = EPI ? bias[col] : 0.0f;
                #pragma unroll
                for (int r = 0; r < 4; ++r) {
                    float v = acc[m][n][r];
                    if (EPI) v = softplus_f(v + bv);
                    Cp[(size_t)(row + r) * ldc + col] = v;
                }
            }
        }
    }
}

// ---------------- xdbl 16-partial reduce (+ bf16 dt_r emit) ----------------
__global__ void xdbl_reduce_kernel(const float* __restrict__ part,
                                   float* __restrict__ out,
                                   ushort* __restrict__ dtr_b) {
    int i = blockIdx.x * 256 + threadIdx.x;   // quad index, 24576 total
    float4 acc = make_float4(0.f, 0.f, 0.f, 0.f);
    #pragma unroll
    for (int s = 0; s < 16; ++s) {
        float4 v = *(const float4*)(part + (size_t)s * SEQ_L * 96 + (size_t)i * 4);
        acc.x += v.x; acc.y += v.y; acc.z += v.z; acc.w += v.w;
    }
    *(float4*)(out + (size_t)i * 4) = acc;
    int c = (i * 4) % 96;
    if (c < 64) {
        int r = (i * 4) / 96;
        ushort4 o;
        o.x = f2bf(acc.x); o.y = f2bf(acc.y); o.z = f2bf(acc.z); o.w = f2bf(acc.w);
        *(ushort4*)(dtr_b + (size_t)r * 64 + c) = o;
    }
}

// ---------------- depthwise causal conv (k=4) + silu ----------------
__global__ void conv_silu_kernel(const float* __restrict__ xz,
                                 const float* __restrict__ cw,
                                 const float* __restrict__ cb,
                                 float* __restrict__ u,
                                 ushort* __restrict__ u_b) {
    int idx = blockIdx.x * 256 + threadIdx.x;
    int l = idx >> 11;
    int c = idx & 2047;
    float acc = cb[c];
    float w0 = cw[c * 4 + 0], w1 = cw[c * 4 + 1], w2 = cw[c * 4 + 2], w3 = cw[c * 4 + 3];
    if (l >= 3) acc = fmaf(xz[(size_t)(l - 3) * 4096 + c], w0, acc);
    if (l >= 2) acc = fmaf(xz[(size_t)(l - 2) * 4096 + c], w1, acc);
    if (l >= 1) acc = fmaf(xz[(size_t)(l - 1) * 4096 + c], w2, acc);
    acc = fmaf(xz[(size_t)l * 4096 + c], w3, acc);
    float s = silu_f(acc);
    u[idx] = s;
    u_b[idx] = f2bf(s);
}

// ---------------- chunked selective scan (CLEN=16, NCHUNK=64) ----------------
__global__ void scan_a_kernel(const float* __restrict__ u,
                              const float* __restrict__ dt,
                              const float* __restrict__ xdbl,
                              const float* __restrict__ A_log,
                              float* __restrict__ yloc,
                              float* __restrict__ cumdt,
                              float* __restrict__ s_end) {
    const int idx = blockIdx.x * 256 + threadIdx.x;   // 131072
    const int d = idx & 2047;
    const int c = idx >> 11;

    float Aa[16];
    #pragma unroll
    for (int q = 0; q < 4; ++q) {
        float4 al = *(const float4*)(A_log + (size_t)d * 16 + q * 4);
        Aa[q * 4 + 0] = -__expf(al.x);
        Aa[q * 4 + 1] = -__expf(al.y);
        Aa[q * 4 + 2] = -__expf(al.z);
        Aa[q * 4 + 3] = -__expf(al.w);
    }

    float s[16];
    #pragma unroll
    for (int n = 0; n < 16; ++n) s[n] = 0.0f;
    float cd = 0.0f;

    const int l0 = c * CLEN;
    for (int i = 0; i < CLEN; ++i) {
        const int l = l0 + i;
        const float dtl = dt[(size_t)l * 2048 + d];
        const float ul  = u[(size_t)l * 2048 + d];
        float Bn[16], Cn[16];
        const float* xbp = xdbl + (size_t)l * 96;
        *(float4*)&Bn[0]  = *(const float4*)(xbp + 64);
        *(float4*)&Bn[4]  = *(const float4*)(xbp + 68);
        *(float4*)&Bn[8]  = *(const float4*)(xbp + 72);
        *(float4*)&Bn[12] = *(const float4*)(xbp + 76);
        *(float4*)&Cn[0]  = *(const float4*)(xbp + 80);
        *(float4*)&Cn[4]  = *(const float4*)(xbp + 84);
        *(float4*)&Cn[8]  = *(const float4*)(xbp + 88);
        *(float4*)&Cn[12] = *(const float4*)(xbp + 92);
        cd += dtl;
        const float dtu = dtl * ul;
        float y = 0.0f;
        #pragma unroll
        for (int n = 0; n < 16; ++n) {
            float dA = __expf(dtl * Aa[n]);
            s[n] = fmaf(s[n], dA, dtu * Bn[n]);
            y = fmaf(s[n], Cn[n], y);
        }
        yloc[(size_t)l * 4096 + d] = y;
        cumdt[(size_t)l * 2048 + d] = cd;
    }
    float* se = s_end + ((size_t)d * NCHUNK + c) * 16;
    #pragma unroll
    for (int q = 0; q < 4; ++q)
        *(float4*)(se + q * 4) = make_float4(s[q * 4], s[q * 4 + 1], s[q * 4 + 2], s[q * 4 + 3]);
}

__global__ void scan_b_kernel(const float* __restrict__ s_end,
                              const float* __restrict__ cumdt,
                              const float* __restrict__ A_log,
                              float* __restrict__ s_in) {
    const int idx = blockIdx.x * 256 + threadIdx.x;   // 32768
    const int d = idx >> 4;
    const int n = idx & 15;
    const float Aa = -__expf(A_log[(size_t)d * 16 + n]);
    float s = 0.0f;
    #pragma unroll 8
    for (int c = 0; c < NCHUNK; ++c) {
        s_in[((size_t)d * NCHUNK + c) * 16 + n] = s;
        const float tot = cumdt[(size_t)(c * CLEN + CLEN - 1) * 2048 + d];
        s = s_end[((size_t)d * NCHUNK + c) * 16 + n] + __expf(Aa * tot) * s;
    }
}

__global__ void scan_c_kernel(const float* __restrict__ u,
                              const float* __restrict__ xdbl,
                              const float* __restrict__ A_log,
                              const float* __restrict__ Dv,
                              const float* __restrict__ xz,
                              const float* __restrict__ cumdt,
                              const float* __restrict__ s_in,
                              ushort* __restrict__ yb) {
    const int idx = blockIdx.x * 256 + threadIdx.x;   // l*2048+d
    const int l = idx >> 11;
    const int d = idx & 2047;
    const int c = l >> 4;   // CLEN=16

    const float cd = cumdt[idx];
    const float ul = u[idx];
    const float yv = xz[(size_t)l * 4096 + d];
    const float zv = xz[(size_t)l * 4096 + 2048 + d];
    const float* Cp = xdbl + (size_t)l * 96 + 80;
    const float* si = s_in + ((size_t)d * NCHUNK + c) * 16;

    float corr = 0.0f;
    #pragma unroll
    for (int q = 0; q < 4; ++q) {
        float4 al = *(const float4*)(A_log + (size_t)d * 16 + q * 4);
        float4 cv = *(const float4*)(Cp + q * 4);
        float4 sv = *(const float4*)(si + q * 4);
        corr = fmaf(cv.x * __expf(-__expf(al.x) * cd), sv.x, corr);
        corr = fmaf(cv.y * __expf(-__expf(al.y) * cd), sv.y, corr);
        corr = fmaf(cv.z * __expf(-__expf(al.z) * cd), sv.z, corr);
        corr = fmaf(cv.w * __expf(-__expf(al.w) * cd), sv.w, corr);
    }
    const float y = (yv + corr + Dv[d] * ul) * silu_f(zv);
    yb[idx] = f2bf(y);
}

extern "C" void kernel_launch(void* const* d_in, const int* in_sizes, int n_in,
                              void* d_out, int out_size, void* d_ws, size_t ws_size,
                              hipStream_t stream) {
    const int*   ids        = (const int*)d_in[0];
    const float* emb        = (const float*)d_in[1];
    const float* norm_w     = (const float*)d_in[2];
    const float* in_proj_w  = (const float*)d_in[3];
    const float* conv_w     = (const float*)d_in[4];
    const float* conv_b     = (const float*)d_in[5];
    const float* x_proj_w   = (const float*)d_in[6];
    const float* dt_proj_w  = (const float*)d_in[7];
    const float* dt_proj_b  = (const float*)d_in[8];
    const float* A_log      = (const float*)d_in[9];
    const float* Dv         = (const float*)d_in[10];
    const float* out_proj_w = (const float*)d_in[11];
    const float* norm_f_w   = (const float*)d_in[12];
    float* out = (float*)d_out;

    // ---- workspace layout ----
    char* p = (char*)d_ws;
    ushort* emb_b  = (ushort*)p; p += (size_t)VOCAB_PAD * D_MODEL * 2;      // 103 MB
    ushort* inw_b  = (ushort*)p; p += (size_t)N_LAYER * 4096 * 1024 * 2;    // 33.6 MB
    ushort* outw_b = (ushort*)p; p += (size_t)N_LAYER * 1024 * 2048 * 2;    // 16.8 MB
    ushort* xpw_b  = (ushort*)p; p += (size_t)N_LAYER * 128 * 2048 * 2;     //  2.1 MB
    ushort* dtw_b  = (ushort*)p; p += (size_t)N_LAYER * 2048 * 64 * 2;      //  1.0 MB
    float* residual = (float*)p; p += (size_t)SEQ_L * D_MODEL * 4;
    float* hpart    = (float*)p; p += (size_t)4 * SEQ_L * D_MODEL * 4;      // 16.8 MB
    float* xdpart   = (float*)p; p += (size_t)16 * SEQ_L * 96 * 4;          //  6.3 MB
    float* xdbl     = (float*)p; p += (size_t)SEQ_L * 96 * 4;
    ushort* dtr_b   = (ushort*)p; p += (size_t)SEQ_L * 64 * 2;              //  0.13 MB
    ushort* xb      = (ushort*)p; p += (size_t)SEQ_L * D_MODEL * 2;
    float* xz       = (float*)p; p += (size_t)SEQ_L * 4096 * 4;
    float* u        = (float*)p; p += (size_t)SEQ_L * 2048 * 4;
    ushort* u_b     = (ushort*)p; p += (size_t)SEQ_L * 2048 * 2;
    float* dtb      = (float*)p; p += (size_t)SEQ_L * 2048 * 4;
    ushort* yb      = (ushort*)p; p += (size_t)SEQ_L * 2048 * 2;
    float* cumdt    = (float*)p; p += (size_t)SEQ_L * 2048 * 4;
    float* s_end    = (float*)p; p += (size_t)D_INNER * NCHUNK * 16 * 4;    //  8.4 MB
    float* s_in     = (float*)p; p += (size_t)D_INNER * NCHUNK * 16 * 4;    //  8.4 MB

    dim3 blk(256);

    // ---- weight conversions (once per launch) ----
    f32_to_bf16_kernel<<<dim3(VOCAB * D_MODEL / 4 / 256), blk, 0, stream>>>(
        emb, emb_b, VOCAB * D_MODEL / 4);
    f32_to_bf16_kernel<<<dim3(N_LAYER * 4096 * 1024 / 4 / 256), blk, 0, stream>>>(
        in_proj_w, inw_b, N_LAYER * 4096 * 1024 / 4);
    f32_to_bf16_kernel<<<dim3(N_LAYER * 1024 * 2048 / 4 / 256), blk, 0, stream>>>(
        out_proj_w, outw_b, N_LAYER * 1024 * 2048 / 4);
    f32_to_bf16_kernel<<<dim3(N_LAYER * 2048 * 64 / 4 / 256), blk, 0, stream>>>(
        dt_proj_w, dtw_b, N_LAYER * 2048 * 64 / 4);
    xpw_convert_kernel<<<dim3(N_LAYER * 128 * 2048 / 4 / 256), blk, 0, stream>>>(
        x_proj_w, xpw_b);

    embed_kernel<<<dim3(SEQ_L), blk, 0, stream>>>(ids, emb, hpart);

    for (int i = 0; i < N_LAYER; ++i) {
        add_rmsnorm_kernel<<<dim3(SEQ_L), blk, 0, stream>>>(
            residual, hpart, norm_w + (size_t)i * D_MODEL, xb,
            i == 0 ? 0 : 1, i == 0 ? 1 : 4);

        // xz = x @ in_proj^T : M=1024 N=4096 K=1024 (NB=32, MB=8 -> 256 blocks)
        gemm_bf16_gld_kernel<0, 0><<<dim3(256), blk, 0, stream>>>(
            xb, inw_b + (size_t)i * 4096 * 1024, xz, nullptr,
            4096, 1024, 1024, 4096, 8, 1, 0);

        conv_silu_kernel<<<dim3(SEQ_L * D_INNER / 256), blk, 0, stream>>>(
            xz, conv_w + (size_t)i * D_INNER * D_CONV, conv_b + (size_t)i * D_INNER,
            u, u_b);

        // xdbl partials: M=1024 N=96 K=2048 (NB=1, MB=8, KS=16 -> 128 blocks)
        gemm_bf16_gld_kernel<1, 0><<<dim3(128), blk, 0, stream>>>(
            u_b, xpw_b + (size_t)i * 128 * 2048, xdpart, nullptr,
            96, 2048, 2048, 96, 8, 16, SEQ_L * 96);
        xdbl_reduce_kernel<<<dim3(SEQ_L * 96 / 4 / 256), blk, 0, stream>>>(
            xdpart, xdbl, dtr_b);

        // dt = softplus(dt_r @ dt_proj^T + b) : M=1024 N=2048 K=64
        // (NB=16, MB=8 -> 128 blocks, MFMA + softplus epilogue)
        gemm_bf16_gld_kernel<0, 1><<<dim3(128), blk, 0, stream>>>(
            dtr_b, dtw_b + (size_t)i * 2048 * 64, dtb,
            dt_proj_b + (size_t)i * D_INNER,
            2048, 64, 64, 2048, 8, 1, 0);

        // chunked scan
        scan_a_kernel<<<dim3(D_INNER * NCHUNK / 256), blk, 0, stream>>>(
            u, dtb, xdbl, A_log + (size_t)i * D_INNER * D_STATE, xz, cumdt, s_end);
        scan_b_kernel<<<dim3(D_INNER * 16 / 256), blk, 0, stream>>>(
            s_end, cumdt, A_log + (size_t)i * D_INNER * D_STATE, s_in);
        scan_c_kernel<<<dim3(SEQ_L * D_INNER / 256), blk, 0, stream>>>(
            u, xdbl, A_log + (size_t)i * D_INNER * D_STATE,
            Dv + (size_t)i * D_INNER, xz, cumdt, s_in, yb);

        // hidden partials = y @ out_proj^T : M=1024 N=1024 K=2048
        // (NB=8, MB=8, KS=4 -> 256 blocks), partial buffers, no atomics
        gemm_bf16_gld_kernel<1, 0><<<dim3(256), blk, 0, stream>>>(
            yb, outw_b + (size_t)i * 1024 * 2048, hpart, nullptr,
            1024, 2048, 2048, 1024, 8, 4, SEQ_L * D_MODEL);
    }

    add_rmsnorm_kernel<<<dim3(SEQ_L), blk, 0, stream>>>(
        residual, hpart, norm_f_w, xb, 1, 4);

    // logits = hf @ emb^T : M=1024 N=50280 K=1024 (NB=393, MB=8 -> 3144 blocks)
    gemm_bf16_gld_kernel<0, 0><<<dim3(3144), blk, 0, stream>>>(
        xb, emb_b, out, nullptr, VOCAB, 1024, 1024, VOCAB, 8, 1, 0);
}

// Round 11
// 795.388 us; speedup vs baseline: 1.0550x; 1.0337x over previous
//
#include <hip/hip_runtime.h>
#include <hip/hip_bf16.h>

#define D_MODEL 1024
#define N_LAYER 4
#define D_INNER 2048
#define D_STATE 16
#define D_CONV  4
#define DT_RANK 64
#define SEQ_L   1024
#define VOCAB   50280
#define VOCAB_PAD 50304   // 393*128
#define NCHUNK  32
#define CLEN    32

typedef __attribute__((ext_vector_type(8))) short short8;
typedef __attribute__((ext_vector_type(4))) float f32x4;

typedef __attribute__((address_space(1))) const unsigned GUint;
typedef __attribute__((address_space(3))) unsigned LUint;

__device__ __forceinline__ float silu_f(float x) {
    return x / (1.0f + __expf(-x));
}
__device__ __forceinline__ float softplus_f(float x) {
    return fmaxf(x, 0.0f) + log1pf(__expf(-fabsf(x)));
}
__device__ __forceinline__ ushort f2bf(float f) {
    union { float f; unsigned u; } uf; uf.f = f;
    unsigned r = uf.u + 0x7FFF + ((uf.u >> 16) & 1);   // RNE
    return (ushort)(r >> 16);
}
__device__ __forceinline__ float bf2f(ushort u) {
    union { unsigned u; float f; } x; x.u = ((unsigned)u) << 16; return x.f;
}

// ---------------- fp32 -> bf16 bulk convert ----------------
__global__ void f32_to_bf16_kernel(const float* __restrict__ in,
                                   ushort* __restrict__ out, int n4) {
    int i = blockIdx.x * 256 + threadIdx.x;
    if (i >= n4) return;
    float4 v = *(const float4*)(in + (size_t)i * 4);
    ushort4 o;
    o.x = f2bf(v.x); o.y = f2bf(v.y); o.z = f2bf(v.z); o.w = f2bf(v.w);
    *(ushort4*)(out + (size_t)i * 4) = o;
}

// x_proj weights: (4,96,2048) fp32 -> (4,128,2048) bf16 with zero-filled pad rows
__global__ void xpw_convert_kernel(const float* __restrict__ src,
                                   ushort* __restrict__ dst) {
    int q = blockIdx.x * 256 + threadIdx.x;   // quad index, total 4*128*512
    int layer = q / (128 * 512);
    int rq    = q % (128 * 512);
    int row   = rq / 512;
    int cq    = rq % 512;
    ushort4 o;
    if (row < 96) {
        float4 v = *(const float4*)(src + ((size_t)layer * 96 + row) * 2048 + cq * 4);
        o.x = f2bf(v.x); o.y = f2bf(v.y); o.z = f2bf(v.z); o.w = f2bf(v.w);
    } else {
        o.x = o.y = o.z = o.w = 0;
    }
    *(ushort4*)(dst + (size_t)q * 4) = o;
}

// ---------------- embedding gather (writes part slot 0) ----------------
__global__ void embed_kernel(const int* __restrict__ ids,
                             const float* __restrict__ emb,
                             float* __restrict__ hidden) {
    int l = blockIdx.x;
    int t = threadIdx.x;
    int id = ids[l];
    float4 v = *(const float4*)(emb + (size_t)id * D_MODEL + t * 4);
    *(float4*)(hidden + (size_t)l * D_MODEL + t * 4) = v;
}

// ---------------- residual add + RMSNorm -> bf16 x ----------------
__global__ void add_rmsnorm_kernel(float* __restrict__ res,
                                   const float* __restrict__ part,
                                   const float* __restrict__ w,
                                   ushort* __restrict__ xout,
                                   int add, int nparts) {
    int l = blockIdx.x;
    int t = threadIdx.x;
    size_t base = (size_t)l * D_MODEL + t * 4;
    float4 r;
    if (add) r = *(const float4*)(res + base);
    else     r = make_float4(0.f, 0.f, 0.f, 0.f);
    for (int s = 0; s < nparts; ++s) {
        float4 hv = *(const float4*)(part + (size_t)s * SEQ_L * D_MODEL + base);
        r.x += hv.x; r.y += hv.y; r.z += hv.z; r.w += hv.w;
    }
    *(float4*)(res + base) = r;
    float ss = r.x * r.x + r.y * r.y + r.z * r.z + r.w * r.w;
    #pragma unroll
    for (int off = 32; off > 0; off >>= 1) ss += __shfl_down(ss, off, 64);
    __shared__ float sred[4];
    if ((t & 63) == 0) sred[t >> 6] = ss;
    __syncthreads();
    float tot = sred[0] + sred[1] + sred[2] + sred[3];
    float scale = rsqrtf(tot * (1.0f / (float)D_MODEL) + 1e-5f);
    float4 wv = *(const float4*)(w + t * 4);
    ushort4 o;
    o.x = f2bf(r.x * scale * wv.x);
    o.y = f2bf(r.y * scale * wv.y);
    o.z = f2bf(r.z * scale * wv.z);
    o.w = f2bf(r.w * scale * wv.w);
    *(ushort4*)(xout + base) = o;
}

// ---------------- bf16 MFMA TN GEMM, global_load_lds staging ----------------
// 128x128 tile, 4 waves, linear LDS, double-buffered, 1 barrier/K-step.
// Source-chunk pre-swizzle + matching read XOR -> 0 bank conflicts.
// SPLIT=1: K-split partial outputs to C + ks*pstride (non-atomic).
// OUTB=1: bf16 output (ushort*).
template<int SPLIT, int OUTB>
__global__ void gemm_bf16_gld_kernel(const ushort* __restrict__ A,
                                     const ushort* __restrict__ W,
                                     void* __restrict__ Cv,
                                     int N, int K, int lda, int ldc,
                                     int MB, int KS, int pstride) {
    __shared__ ushort As[2][128][32];
    __shared__ ushort Ws[2][128][32];
    const int t  = threadIdx.x;
    const int T  = gridDim.x >> 3;
    const int id = blockIdx.x;
    const int j  = (id & 7) * T + (id >> 3);
    const int ks  = j % KS;
    const int rem = j / KS;
    const int m0 = (rem % MB) * 128;
    const int n0 = (rem / MB) * 128;
    const int kchunk = K / KS;
    const int kbeg = ks * kchunk;
    const int kend = kbeg + kchunk;

    const int lane = t & 63;
    const int w    = t >> 6;                 // wave 0..3
    const int srow = w * 16 + (lane >> 2);
    const int scol = (((lane & 3) ^ ((lane >> 3) & 3)) * 8);   // swizzled src chunk
    const ushort* Ag0 = A + (size_t)(m0 + srow) * lda + scol;
    const ushort* Ag1 = A + (size_t)(m0 + srow + 64) * lda + scol;
    const ushort* Wg0 = W + (size_t)(n0 + srow) * K + scol;
    const ushort* Wg1 = W + (size_t)(n0 + srow + 64) * K + scol;

    const int wm = (t >> 7) & 1;
    const int wn = (t >> 6) & 1;
    const int lr = lane & 15;
    const int lk = lane >> 4;
    const int swz = (lr >> 1) & 3;           // read-side XOR pattern

    f32x4 acc[4][4] = {};

#define STAGE_GLD(buf, kk)                                                        \
    do {                                                                          \
        __builtin_amdgcn_global_load_lds((GUint*)(Ag0 + (kk)),                    \
            (LUint*)&As[buf][w * 16][0], 16, 0, 0);                               \
        __builtin_amdgcn_global_load_lds((GUint*)(Ag1 + (kk)),                    \
            (LUint*)&As[buf][64 + w * 16][0], 16, 0, 0);                          \
        __builtin_amdgcn_global_load_lds((GUint*)(Wg0 + (kk)),                    \
            (LUint*)&Ws[buf][w * 16][0], 16, 0, 0);                               \
        __builtin_amdgcn_global_load_lds((GUint*)(Wg1 + (kk)),                    \
            (LUint*)&Ws[buf][64 + w * 16][0], 16, 0, 0);                          \
    } while (0)

    STAGE_GLD(0, kbeg);
    int buf = 0;
    for (int k0 = kbeg;;) {
        __syncthreads();
        const bool more = (k0 + 32) < kend;
        if (more) STAGE_GLD(buf ^ 1, k0 + 32);

        short8 af[4], bfr[4];
        #pragma unroll
        for (int m = 0; m < 4; ++m)
            af[m] = *(const short8*)&As[buf][wm * 64 + m * 16 + lr][(lk ^ swz) * 8];
        #pragma unroll
        for (int n = 0; n < 4; ++n)
            bfr[n] = *(const short8*)&Ws[buf][wn * 64 + n * 16 + lr][(lk ^ swz) * 8];
        #pragma unroll
        for (int m = 0; m < 4; ++m)
            #pragma unroll
            for (int n = 0; n < 4; ++n)
                acc[m][n] = __builtin_amdgcn_mfma_f32_16x16x32_bf16(
                    af[m], bfr[n], acc[m][n], 0, 0, 0);

        if (!more) break;
        buf ^= 1;
        k0 += 32;
    }
#undef STAGE_GLD

    float*  Cf = SPLIT ? ((float*)Cv + (size_t)ks * pstride) : (float*)Cv;
    ushort* Cb = (ushort*)Cv;
    #pragma unroll
    for (int m = 0; m < 4; ++m) {
        const int row = m0 + wm * 64 + m * 16 + lk * 4;
        #pragma unroll
        for (int n = 0; n < 4; ++n) {
            const int col = n0 + wn * 64 + n * 16 + lr;
            if (col < N) {
                #pragma unroll
                for (int r = 0; r < 4; ++r) {
                    if (OUTB)
                        Cb[(size_t)(row + r) * ldc + col] = f2bf(acc[m][n][r]);
                    else
                        Cf[(size_t)(row + r) * ldc + col] = acc[m][n][r];
                }
            }
        }
    }
}

// ---------------- xdbl 16-partial reduce ----------------
__global__ void xdbl_reduce_kernel(const float* __restrict__ part,
                                   float* __restrict__ out) {
    int i = blockIdx.x * 256 + threadIdx.x;   // quad index, 24576 total
    float4 acc = make_float4(0.f, 0.f, 0.f, 0.f);
    #pragma unroll
    for (int s = 0; s < 16; ++s) {
        float4 v = *(const float4*)(part + (size_t)s * SEQ_L * 96 + (size_t)i * 4);
        acc.x += v.x; acc.y += v.y; acc.z += v.z; acc.w += v.w;
    }
    *(float4*)(out + (size_t)i * 4) = acc;
}

// ---------------- fp32 TN GEMM (dt_proj only) ----------------
template<int EPI>
__global__ void gemm_tn_kernel(const float* __restrict__ A,
                               const float* __restrict__ W,
                               const float* __restrict__ bias,
                               float* __restrict__ C,
                               int M, int N, int K, int lda) {
    __shared__ float As[16][68];
    __shared__ float Ws[16][68];
    const int t  = threadIdx.x;
    const int m0 = blockIdx.y * 64;
    const int n0 = blockIdx.x * 64;
    const int lrow = t >> 2;
    const int lkq  = (t & 3) * 4;
    const int tx = t & 15;
    const int ty = t >> 4;

    const float* Arow = A + (size_t)(m0 + lrow) * lda;
    const int   wr    = n0 + lrow;
    const bool  wvalid = wr < N;
    const float* Wrow = W + (size_t)(wvalid ? wr : 0) * K;

    float acc[4][4] = {};
    for (int k0 = 0; k0 < K; k0 += 16) {
        float4 av = *(const float4*)(Arow + k0 + lkq);
        float4 wv = wvalid ? *(const float4*)(Wrow + k0 + lkq)
                           : make_float4(0.f, 0.f, 0.f, 0.f);
        As[lkq + 0][lrow] = av.x; As[lkq + 1][lrow] = av.y;
        As[lkq + 2][lrow] = av.z; As[lkq + 3][lrow] = av.w;
        Ws[lkq + 0][lrow] = wv.x; Ws[lkq + 1][lrow] = wv.y;
        Ws[lkq + 2][lrow] = wv.z; Ws[lkq + 3][lrow] = wv.w;
        __syncthreads();
        #pragma unroll
        for (int kk = 0; kk < 16; ++kk) {
            float4 a = *(const float4*)&As[kk][ty * 4];
            float4 b = *(const float4*)&Ws[kk][tx * 4];
            #pragma unroll
            for (int i = 0; i < 4; ++i) {
                float ai = (i == 0) ? a.x : (i == 1) ? a.y : (i == 2) ? a.z : a.w;
                acc[i][0] = fmaf(ai, b.x, acc[i][0]);
                acc[i][1] = fmaf(ai, b.y, acc[i][1]);
                acc[i][2] = fmaf(ai, b.z, acc[i][2]);
                acc[i][3] = fmaf(ai, b.w, acc[i][3]);
            }
        }
        __syncthreads();
    }

    const int colb = n0 + tx * 4;
    if (colb < N) {
        #pragma unroll
        for (int i = 0; i < 4; ++i) {
            int row = m0 + ty * 4 + i;
            float4 v = make_float4(acc[i][0], acc[i][1], acc[i][2], acc[i][3]);
            if (EPI == 1) {
                v.x = softplus_f(v.x + bias[colb + 0]);
                v.y = softplus_f(v.y + bias[colb + 1]);
                v.z = softplus_f(v.z + bias[colb + 2]);
                v.w = softplus_f(v.w + bias[colb + 3]);
            }
            *(float4*)(C + (size_t)row * N + colb) = v;
        }
    }
}

// ---------------- depthwise causal conv (k=4) + silu, bf16 in/out ----------------
__global__ void conv_silu_kernel(const ushort* __restrict__ xz,
                                 const float* __restrict__ cw,
                                 const float* __restrict__ cb,
                                 ushort* __restrict__ u_b) {
    int idx = blockIdx.x * 256 + threadIdx.x;
    int l = idx >> 11;
    int c = idx & 2047;
    float acc = cb[c];
    float w0 = cw[c * 4 + 0], w1 = cw[c * 4 + 1], w2 = cw[c * 4 + 2], w3 = cw[c * 4 + 3];
    if (l >= 3) acc = fmaf(bf2f(xz[(size_t)(l - 3) * 4096 + c]), w0, acc);
    if (l >= 2) acc = fmaf(bf2f(xz[(size_t)(l - 2) * 4096 + c]), w1, acc);
    if (l >= 1) acc = fmaf(bf2f(xz[(size_t)(l - 1) * 4096 + c]), w2, acc);
    acc = fmaf(bf2f(xz[(size_t)l * 4096 + c]), w3, acc);
    u_b[idx] = f2bf(silu_f(acc));
}

// ---------------- chunked selective scan ----------------
__global__ void scan_a_kernel(const ushort* __restrict__ u_b,
                              const float* __restrict__ dt,
                              const float* __restrict__ xdbl,
                              const float* __restrict__ A_log,
                              ushort* __restrict__ yloc,    // bf16, stride 4096 (xz xp half)
                              float* __restrict__ cumdt,
                              float* __restrict__ s_end) {
    const int idx = blockIdx.x * 256 + threadIdx.x;   // 65536
    const int d = idx & 2047;
    const int c = idx >> 11;

    float Aa[16];
    #pragma unroll
    for (int q = 0; q < 4; ++q) {
        float4 al = *(const float4*)(A_log + (size_t)d * 16 + q * 4);
        Aa[q * 4 + 0] = -__expf(al.x);
        Aa[q * 4 + 1] = -__expf(al.y);
        Aa[q * 4 + 2] = -__expf(al.z);
        Aa[q * 4 + 3] = -__expf(al.w);
    }

    float s[16];
    #pragma unroll
    for (int n = 0; n < 16; ++n) s[n] = 0.0f;
    float cd = 0.0f;

    const int l0 = c * CLEN;
    for (int i = 0; i < CLEN; ++i) {
        const int l = l0 + i;
        const float dtl = dt[(size_t)l * 2048 + d];
        const float ul  = bf2f(u_b[(size_t)l * 2048 + d]);
        float Bn[16], Cn[16];
        const float* xbp = xdbl + (size_t)l * 96;
        *(float4*)&Bn[0]  = *(const float4*)(xbp + 64);
        *(float4*)&Bn[4]  = *(const float4*)(xbp + 68);
        *(float4*)&Bn[8]  = *(const float4*)(xbp + 72);
        *(float4*)&Bn[12] = *(const float4*)(xbp + 76);
        *(float4*)&Cn[0]  = *(const float4*)(xbp + 80);
        *(float4*)&Cn[4]  = *(const float4*)(xbp + 84);
        *(float4*)&Cn[8]  = *(const float4*)(xbp + 88);
        *(float4*)&Cn[12] = *(const float4*)(xbp + 92);
        cd += dtl;
        const float dtu = dtl * ul;
        float y = 0.0f;
        #pragma unroll
        for (int n = 0; n < 16; ++n) {
            float dA = __expf(dtl * Aa[n]);
            s[n] = fmaf(s[n], dA, dtu * Bn[n]);
            y = fmaf(s[n], Cn[n], y);
        }
        yloc[(size_t)l * 4096 + d] = f2bf(y);
        cumdt[(size_t)l * 2048 + d] = cd;
    }
    float* se = s_end + ((size_t)d * NCHUNK + c) * 16;
    #pragma unroll
    for (int q = 0; q < 4; ++q)
        *(float4*)(se + q * 4) = make_float4(s[q * 4], s[q * 4 + 1], s[q * 4 + 2], s[q * 4 + 3]);
}

__global__ void scan_b_kernel(const float* __restrict__ s_end,
                              const float* __restrict__ cumdt,
                              const float* __restrict__ A_log,
                              float* __restrict__ s_in) {
    const int idx = blockIdx.x * 256 + threadIdx.x;   // 32768
    const int d = idx >> 4;
    const int n = idx & 15;
    const float Aa = -__expf(A_log[(size_t)d * 16 + n]);
    float s = 0.0f;
    #pragma unroll
    for (int c = 0; c < NCHUNK; ++c) {
        s_in[((size_t)d * NCHUNK + c) * 16 + n] = s;
        const float tot = cumdt[(size_t)(c * CLEN + CLEN - 1) * 2048 + d];
        s = s_end[((size_t)d * NCHUNK + c) * 16 + n] + __expf(Aa * tot) * s;
    }
}

__global__ void scan_c_kernel(const ushort* __restrict__ u_b,
                              const float* __restrict__ xdbl,
                              const float* __restrict__ A_log,
                              const float* __restrict__ Dv,
                              const ushort* __restrict__ xz,   // bf16: yloc in xp half, z in z half
                              const float* __restrict__ cumdt,
                              const float* __restrict__ s_in,
                              ushort* __restrict__ yb) {
    const int idx = blockIdx.x * 256 + threadIdx.x;   // l*2048+d
    const int l = idx >> 11;
    const int d = idx & 2047;
    const int c = l >> 5;   // CLEN=32

    const float cd = cumdt[idx];
    const float ul = bf2f(u_b[idx]);
    const float yv = bf2f(xz[(size_t)l * 4096 + d]);
    const float zv = bf2f(xz[(size_t)l * 4096 + 2048 + d]);
    const float* Cp = xdbl + (size_t)l * 96 + 80;
    const float* si = s_in + ((size_t)d * NCHUNK + c) * 16;

    float corr = 0.0f;
    #pragma unroll
    for (int q = 0; q < 4; ++q) {
        float4 al = *(const float4*)(A_log + (size_t)d * 16 + q * 4);
        float4 cv = *(const float4*)(Cp + q * 4);
        float4 sv = *(const float4*)(si + q * 4);
        corr = fmaf(cv.x * __expf(-__expf(al.x) * cd), sv.x, corr);
        corr = fmaf(cv.y * __expf(-__expf(al.y) * cd), sv.y, corr);
        corr = fmaf(cv.z * __expf(-__expf(al.z) * cd), sv.z, corr);
        corr = fmaf(cv.w * __expf(-__expf(al.w) * cd), sv.w, corr);
    }
    const float y = (yv + corr + Dv[d] * ul) * silu_f(zv);
    yb[idx] = f2bf(y);
}

extern "C" void kernel_launch(void* const* d_in, const int* in_sizes, int n_in,
                              void* d_out, int out_size, void* d_ws, size_t ws_size,
                              hipStream_t stream) {
    const int*   ids        = (const int*)d_in[0];
    const float* emb        = (const float*)d_in[1];
    const float* norm_w     = (const float*)d_in[2];
    const float* in_proj_w  = (const float*)d_in[3];
    const float* conv_w     = (const float*)d_in[4];
    const float* conv_b     = (const float*)d_in[5];
    const float* x_proj_w   = (const float*)d_in[6];
    const float* dt_proj_w  = (const float*)d_in[7];
    const float* dt_proj_b  = (const float*)d_in[8];
    const float* A_log      = (const float*)d_in[9];
    const float* Dv         = (const float*)d_in[10];
    const float* out_proj_w = (const float*)d_in[11];
    const float* norm_f_w   = (const float*)d_in[12];
    float* out = (float*)d_out;

    // ---- workspace layout (round-7 structure, xz now bf16) ----
    char* p = (char*)d_ws;
    ushort* emb_b  = (ushort*)p; p += (size_t)VOCAB_PAD * D_MODEL * 2;      // 103 MB
    ushort* inw_b  = (ushort*)p; p += (size_t)N_LAYER * 4096 * 1024 * 2;    // 33.6 MB
    ushort* outw_b = (ushort*)p; p += (size_t)N_LAYER * 1024 * 2048 * 2;    // 16.8 MB
    ushort* xpw_b  = (ushort*)p; p += (size_t)N_LAYER * 128 * 2048 * 2;     //  2.1 MB
    float* residual = (float*)p; p += (size_t)SEQ_L * D_MODEL * 4;
    float* hpart    = (float*)p; p += (size_t)4 * SEQ_L * D_MODEL * 4;      // 16.8 MB
    float* xdpart   = (float*)p; p += (size_t)16 * SEQ_L * 96 * 4;          //  6.3 MB
    float* xdbl     = (float*)p; p += (size_t)SEQ_L * 96 * 4;
    ushort* xb      = (ushort*)p; p += (size_t)SEQ_L * D_MODEL * 2;
    ushort* xzb     = (ushort*)p; p += (size_t)SEQ_L * 4096 * 2;            //  8.4 MB (bf16)
    ushort* u_b     = (ushort*)p; p += (size_t)SEQ_L * 2048 * 2;
    float* dtb      = (float*)p; p += (size_t)SEQ_L * 2048 * 4;
    ushort* yb      = (ushort*)p; p += (size_t)SEQ_L * 2048 * 2;
    float* cumdt    = (float*)p; p += (size_t)SEQ_L * 2048 * 4;
    float* s_end    = (float*)p; p += (size_t)D_INNER * NCHUNK * 16 * 4;
    float* s_in     = (float*)p; p += (size_t)D_INNER * NCHUNK * 16 * 4;

    dim3 blk(256);

    // ---- weight conversions (once per launch) ----
    f32_to_bf16_kernel<<<dim3(VOCAB * D_MODEL / 4 / 256), blk, 0, stream>>>(
        emb, emb_b, VOCAB * D_MODEL / 4);
    f32_to_bf16_kernel<<<dim3(N_LAYER * 4096 * 1024 / 4 / 256), blk, 0, stream>>>(
        in_proj_w, inw_b, N_LAYER * 4096 * 1024 / 4);
    f32_to_bf16_kernel<<<dim3(N_LAYER * 1024 * 2048 / 4 / 256), blk, 0, stream>>>(
        out_proj_w, outw_b, N_LAYER * 1024 * 2048 / 4);
    xpw_convert_kernel<<<dim3(N_LAYER * 128 * 2048 / 4 / 256), blk, 0, stream>>>(
        x_proj_w, xpw_b);

    embed_kernel<<<dim3(SEQ_L), blk, 0, stream>>>(ids, emb, hpart);

    for (int i = 0; i < N_LAYER; ++i) {
        add_rmsnorm_kernel<<<dim3(SEQ_L), blk, 0, stream>>>(
            residual, hpart, norm_w + (size_t)i * D_MODEL, xb,
            i == 0 ? 0 : 1, i == 0 ? 1 : 4);

        // xz (bf16) = x @ in_proj^T : M=1024 N=4096 K=1024 (256 blocks)
        gemm_bf16_gld_kernel<0, 1><<<dim3(256), blk, 0, stream>>>(
            xb, inw_b + (size_t)i * 4096 * 1024, xzb, 4096, 1024, 1024, 4096, 8, 1, 0);

        conv_silu_kernel<<<dim3(SEQ_L * D_INNER / 256), blk, 0, stream>>>(
            xzb, conv_w + (size_t)i * D_INNER * D_CONV, conv_b + (size_t)i * D_INNER,
            u_b);

        // xdbl partials: M=1024 N=96 K=2048 (NB=1, MB=8, KS=16 -> 128 blocks)
        gemm_bf16_gld_kernel<1, 0><<<dim3(128), blk, 0, stream>>>(
            u_b, xpw_b + (size_t)i * 128 * 2048, xdpart, 96, 2048, 2048, 96,
            8, 16, SEQ_L * 96);
        xdbl_reduce_kernel<<<dim3(SEQ_L * 96 / 4 / 256), blk, 0, stream>>>(
            xdpart, xdbl);

        // dt = softplus(dt_r @ dt_proj^T + b) : fp32, M=1024 N=2048 K=64
        gemm_tn_kernel<1><<<dim3(D_INNER / 64, SEQ_L / 64), blk, 0, stream>>>(
            xdbl, dt_proj_w + (size_t)i * D_INNER * DT_RANK,
            dt_proj_b + (size_t)i * D_INNER, dtb,
            SEQ_L, D_INNER, DT_RANK, 96);

        // chunked scan
        scan_a_kernel<<<dim3(D_INNER * NCHUNK / 256), blk, 0, stream>>>(
            u_b, dtb, xdbl, A_log + (size_t)i * D_INNER * D_STATE, xzb, cumdt, s_end);
        scan_b_kernel<<<dim3(D_INNER * 16 / 256), blk, 0, stream>>>(
            s_end, cumdt, A_log + (size_t)i * D_INNER * D_STATE, s_in);
        scan_c_kernel<<<dim3(SEQ_L * D_INNER / 256), blk, 0, stream>>>(
            u_b, xdbl, A_log + (size_t)i * D_INNER * D_STATE,
            Dv + (size_t)i * D_INNER, xzb, cumdt, s_in, yb);

        // hidden partials = y @ out_proj^T : M=1024 N=1024 K=2048
        // (NB=8, MB=8, KS=4 -> 256 blocks), partial buffers, no atomics
        gemm_bf16_gld_kernel<1, 0><<<dim3(256), blk, 0, stream>>>(
            yb, outw_b + (size_t)i * 1024 * 2048, hpart, 1024, 2048, 2048, 1024,
            8, 4, SEQ_L * D_MODEL);
    }

    add_rmsnorm_kernel<<<dim3(SEQ_L), blk, 0, stream>>>(
        residual, hpart, norm_f_w, xb, 1, 4);

    // logits = hf @ emb^T : M=1024 N=50280 K=1024 (NB=393, MB=8 -> 3144 blocks)
    gemm_bf16_gld_kernel<0, 0><<<dim3(3144), blk, 0, stream>>>(
        xb, emb_b, out, VOCAB, 1024, 1024, VOCAB, 8, 1, 0);
}